// Round 13
// baseline (1748.002 us; speedup 1.0000x reference)
//
#include <hip/hip_runtime.h>
#include <hip/hip_bf16.h>

#define S_LEN  2048
#define HDIM   2048
#define NH_    16
#define DQK_   192
#define QRANK_ 1024
#define KVRANK_ 512
#define KVDN   576
#define DCAT   1600   // QRANK + KVDN merged down-proj width
#define KVUPN  4096
#define QN_    3072
#define IFF_   1408
#define IFF2   2816   // interleaved w1|w3 width
#define EXP_   8
#define PD_    4096

typedef __attribute__((ext_vector_type(8))) short   short8_t;
typedef __attribute__((ext_vector_type(8))) __bf16  bf16x8_t;
typedef __attribute__((ext_vector_type(4))) float   f32x4;

static __device__ __forceinline__ float b2f(short s) {
  unsigned int u = ((unsigned int)(unsigned short)s) << 16;
  return __builtin_bit_cast(float, u);
}
static __device__ __forceinline__ short f2b(float f) {
  return __builtin_bit_cast(short, __float2bfloat16(f));
}

static __device__ __forceinline__ void gload16(const void* g, void* l) {
  __builtin_amdgcn_global_load_lds(
      (const __attribute__((address_space(1))) void*)g,
      (__attribute__((address_space(3))) void*)l,
      16, 0, 0);
}
static __device__ __forceinline__ void wait_vm6() { asm volatile("s_waitcnt vmcnt(6)" ::: "memory"); }
static __device__ __forceinline__ void wait_vm2() { asm volatile("s_waitcnt vmcnt(2)" ::: "memory"); }
static __device__ __forceinline__ void wait_vm0() { asm volatile("s_waitcnt vmcnt(0)" ::: "memory"); }

// ---------------- dtype detect + convert ----------------
__global__ void __launch_bounds__(256)
detect_kernel(const void* probe, int* flag) {
  const float* f = (const float*)probe;
  int tid = threadIdx.x;
  int cnt = 0;
  for (int i = tid; i < 2048; i += 256) {
    float v = fabsf(f[i]);
    if (v > 1e-6f && v < 10.0f) cnt++;
  }
  __shared__ int red[256];
  red[tid] = cnt; __syncthreads();
  for (int s = 128; s > 0; s >>= 1) {
    if (tid < s) red[tid] += red[tid + s];
    __syncthreads();
  }
  if (tid == 0) *flag = (red[0] > 1600) ? 1 : 0;
}

__global__ void __launch_bounds__(256)
convert_kernel(const void* src, short* dst, long long nchunks, const int* flag) {
  long long idx = (long long)blockIdx.x * 256 + threadIdx.x;
  long long stride = (long long)gridDim.x * 256;
  if (*flag) {
    const f32x4* s = (const f32x4*)src;
    for (long long c = idx; c < nchunks; c += stride) {
      f32x4 a = s[2 * c], b = s[2 * c + 1];
      short8_t o;
      #pragma unroll
      for (int j = 0; j < 4; ++j) { o[j] = f2b(a[j]); o[4 + j] = f2b(b[j]); }
      reinterpret_cast<short8_t*>(dst)[c] = o;
    }
  } else {
    const short8_t* s = (const short8_t*)src;
    for (long long c = idx; c < nchunks; c += stride)
      reinterpret_cast<short8_t*>(dst)[c] = s[c];
  }
}

// transpose-convert: src slab [R][C] -> dst rows (c*rowMul+rowOff) stride R, bf16
__global__ void __launch_bounds__(256)
transconv_kernel(const void* src, short* dst, int R, int C, const int* flag,
                 long long sSrc, long long sDst, int rowMul, int rowOff) {
  long long zs = (long long)blockIdx.z * sSrc;
  long long zd = (long long)blockIdx.z * sDst;
  int r0 = blockIdx.y * 32, c0 = blockIdx.x * 32;
  int tx = threadIdx.x & 31, ty = threadIdx.x >> 5;
  __shared__ short tile[32][33];
  if (*flag) {
    const float* s = (const float*)src + zs;
    #pragma unroll
    for (int i = 0; i < 4; ++i)
      tile[ty + i * 8][tx] = f2b(s[(long long)(r0 + ty + i * 8) * C + c0 + tx]);
  } else {
    const short* s = (const short*)src + zs;
    #pragma unroll
    for (int i = 0; i < 4; ++i)
      tile[ty + i * 8][tx] = s[(long long)(r0 + ty + i * 8) * C + c0 + tx];
  }
  __syncthreads();
  short* d = dst + zd;
  #pragma unroll
  for (int i = 0; i < 4; ++i)
    d[(long long)((c0 + ty + i * 8) * rowMul + rowOff) * R + r0 + tx] = tile[tx][ty + i * 8];
}

__global__ void __launch_bounds__(256)
embed_convert_kernel(const int* ids, const void* emb, const int* flag, short* h) {
  int s = blockIdx.x;
  long long row = ids[s];
  int c = threadIdx.x;
  short8_t o;
  if (*flag) {
    const f32x4* src = (const f32x4*)((const float*)emb + row * HDIM);
    f32x4 a = src[2 * c], b = src[2 * c + 1];
    #pragma unroll
    for (int j = 0; j < 4; ++j) { o[j] = f2b(a[j]); o[4 + j] = f2b(b[j]); }
  } else {
    o = reinterpret_cast<const short8_t*>((const short*)emb + row * HDIM)[c];
  }
  reinterpret_cast<short8_t*>(h + (long long)s * HDIM)[c] = o;
}

// ---------------- pipelined MFMA GEMM, 128x256 tile (B always [N][K], bf16 C) ----------------
// 4 waves: wm=(w>>1)*64, wn=(w&1)*128; acc[4][8]; 32 MFMA + 6 gload16 per wave per K-step.
// EPI=0: plain store. EPI=1: fused SiLU-pair (even=gate, odd=up), writes N/2 cols. EPI=2: in-place add.
template<int EPI>
__global__ void __launch_bounds__(256, 2)
gemm_kernel(const short* __restrict__ A, const short* __restrict__ B,
            short* __restrict__ Cv, int M, int N, int K,
            int lda, int ldb, int ldc,
            long long sAb, long long sBb, long long sCb)
{
  __shared__ short smem[36864];   // A: 3x4096 @0, B: 3x8192 @12288
  short* shA = smem;
  short* shB = smem + 12288;
  const int tid = threadIdx.x;
  const long long bz = blockIdx.z;
  const short* Ab = A + bz * sAb;
  const short* Bb = B + bz * sBb;
  const int m0 = blockIdx.x * 128;
  const int n0 = blockIdx.y * 256;
  const int w = tid >> 6, lane = tid & 63;
  const int wm = (w >> 1) << 6, wn = (w & 1) << 7;
  const int lr = lane & 15, g = lane >> 4;
  const int srow = lane >> 2;
  const int sunit = ((lane & 3) ^ ((lane >> 3) & 3)) << 3;
  const int rsw = ((g ^ ((lr >> 1) & 3)) << 3);
  const f32x4 vzero = {0.f, 0.f, 0.f, 0.f};
  f32x4 acc[4][8];
  #pragma unroll
  for (int i = 0; i < 4; ++i)
    #pragma unroll
    for (int j = 0; j < 8; ++j) acc[i][j] = vzero;

  const int nt = K >> 5;
#define STAGE_G(bi, kk) do { \
    _Pragma("unroll") \
    for (int r = 0; r < 2; ++r) { \
      int rowb = (w << 4) + (r << 6); \
      gload16(Ab + (long long)(m0 + rowb + srow) * lda + (kk) + sunit, &shA[(bi) * 4096 + rowb * 32]); \
    } \
    _Pragma("unroll") \
    for (int r = 0; r < 4; ++r) { \
      int rowb = (w << 4) + (r << 6); \
      gload16(Bb + (long long)(n0 + rowb + srow) * ldb + (kk) + sunit, &shB[(bi) * 8192 + rowb * 32]); \
    } } while (0)

  STAGE_G(0, 0);
  if (nt > 1) STAGE_G(1, 32);
  int cur = 0, i2 = 2;
  for (int t = 0; t < nt; ++t) {
    if (t + 1 < nt) wait_vm6(); else wait_vm0();
    __builtin_amdgcn_s_barrier();
    if (t + 2 < nt) STAGE_G(i2, (t + 2) << 5);
    short8_t af[4];
    #pragma unroll
    for (int mi = 0; mi < 4; ++mi)
      af[mi] = *reinterpret_cast<const short8_t*>(&shA[cur * 4096 + (wm + (mi << 4) + lr) * 32 + rsw]);
    __builtin_amdgcn_s_setprio(1);
    #pragma unroll
    for (int ni = 0; ni < 8; ++ni) {
      short8_t bfr = *reinterpret_cast<const short8_t*>(&shB[cur * 8192 + (wn + (ni << 4) + lr) * 32 + rsw]);
      #pragma unroll
      for (int mi = 0; mi < 4; ++mi)
        acc[mi][ni] = __builtin_amdgcn_mfma_f32_16x16x32_bf16(
            __builtin_bit_cast(bf16x8_t, af[mi]),
            __builtin_bit_cast(bf16x8_t, bfr),
            acc[mi][ni], 0, 0, 0);
    }
    __builtin_amdgcn_s_setprio(0);
    cur = (cur == 2) ? 0 : cur + 1;
    i2  = (i2 == 2) ? 0 : i2 + 1;
  }
#undef STAGE_G
  // ---- epilogue: two 128-col halves through LDS [128][136] ----
  short* C = Cv + bz * sCb;
  #pragma unroll
  for (int half = 0; half < 2; ++half) {
    __syncthreads();
    if ((w & 1) == half) {
      #pragma unroll
      for (int ni = 0; ni < 8; ++ni)
        #pragma unroll
        for (int mi = 0; mi < 4; ++mi)
          #pragma unroll
          for (int r = 0; r < 4; ++r)
            smem[(wm + (mi << 4) + (g << 2) + r) * 136 + (ni << 4) + lr] = f2b(acc[mi][ni][r]);
    }
    __syncthreads();
    int n0e = n0 + (half << 7);
    int row = tid >> 1, halfc = (tid & 1) << 6;
    if (EPI == 1) {
      int ocol = (n0e >> 1) + (halfc >> 1);
      #pragma unroll
      for (int j = 0; j < 4; ++j) {
        short8_t v0 = *reinterpret_cast<const short8_t*>(&smem[row * 136 + halfc + (j << 4)]);
        short8_t v1 = *reinterpret_cast<const short8_t*>(&smem[row * 136 + halfc + (j << 4) + 8]);
        short8_t o;
        #pragma unroll
        for (int q = 0; q < 4; ++q) {
          float x = b2f(v0[2 * q]);
          o[q] = f2b((x / (1.0f + expf(-x))) * b2f(v0[2 * q + 1]));
          float y = b2f(v1[2 * q]);
          o[4 + q] = f2b((y / (1.0f + expf(-y))) * b2f(v1[2 * q + 1]));
        }
        *reinterpret_cast<short8_t*>(&C[(long long)(m0 + row) * ldc + ocol + (j << 3)]) = o;
      }
    } else {
      #pragma unroll
      for (int j = 0; j < 8; ++j) {
        int col = n0e + halfc + (j << 3);
        if (col + 8 <= N) {
          short8_t v = *reinterpret_cast<const short8_t*>(&smem[row * 136 + halfc + (j << 3)]);
          short* cp = &C[(long long)(m0 + row) * ldc + col];
          if (EPI == 2) {
            short8_t hv = *reinterpret_cast<const short8_t*>(cp);
            short8_t o;
            #pragma unroll
            for (int q = 0; q < 8; ++q) o[q] = f2b(b2f(hv[q]) + b2f(v[q]));
            *reinterpret_cast<short8_t*>(cp) = o;
          } else {
            *reinterpret_cast<short8_t*>(cp) = v;
          }
        }
      }
    }
  }
}

// ---------------- pipelined sparse MoE gather GEMM, 128x256 tile ----------------
// GRID: (n_tiles, m_tiles, experts) — m on Y so early-exit blocks spread across XCDs.
template<int GATHER, int SILU>
__global__ void __launch_bounds__(256, 2)
moe_gemm_kernel(const short* __restrict__ A, const int* __restrict__ elist,
                const int* __restrict__ cnt, const short* __restrict__ B,
                short* __restrict__ C, const float* __restrict__ ewt,
                int N, int K, int lda, int ldb, int ldc,
                long long sAe, long long sBe, long long sCe)
{
  const int e = blockIdx.z;
  const int cnt_e = cnt[e];
  const int m0 = blockIdx.y << 7;
  if (m0 >= cnt_e) return;
  const short* Bb = B + (long long)e * sBe;
  short* Cb = C + (long long)e * sCe;
  const int n0 = blockIdx.x << 8;
  const int tid = threadIdx.x;
  const int w = tid >> 6, lane = tid & 63;
  const int wm = (w >> 1) << 6, wn = (w & 1) << 7;
  const int lr = lane & 15, g = lane >> 4;
  const int srow = lane >> 2;
  const int sunit = ((lane & 3) ^ ((lane >> 3) & 3)) << 3;
  const int rsw = ((g ^ ((lr >> 1) & 3)) << 3);

  long long arow[2];
  #pragma unroll
  for (int r = 0; r < 2; ++r) {
    int row = m0 + (w << 4) + (r << 6) + srow;
    if (GATHER) {
      int p = row > cnt_e - 1 ? cnt_e - 1 : row;
      arow[r] = (long long)elist[e * S_LEN + p] * lda;
    } else {
      arow[r] = (long long)e * sAe + (long long)row * lda;
    }
  }

  __shared__ short smem[36864];
  short* shA = smem;
  short* shB = smem + 12288;
  const f32x4 vzero = {0.f, 0.f, 0.f, 0.f};
  f32x4 acc[4][8];
  #pragma unroll
  for (int i = 0; i < 4; ++i)
    #pragma unroll
    for (int j = 0; j < 8; ++j) acc[i][j] = vzero;

  const int nt = K >> 5;
#define STAGE_M(bi, kk) do { \
    _Pragma("unroll") \
    for (int r = 0; r < 2; ++r) { \
      int rowb = (w << 4) + (r << 6); \
      gload16(A + arow[r] + (kk) + sunit, &shA[(bi) * 4096 + rowb * 32]); \
    } \
    _Pragma("unroll") \
    for (int r = 0; r < 4; ++r) { \
      int rowb = (w << 4) + (r << 6); \
      gload16(Bb + (long long)(n0 + rowb + srow) * ldb + (kk) + sunit, &shB[(bi) * 8192 + rowb * 32]); \
    } } while (0)

  STAGE_M(0, 0);
  if (nt > 1) STAGE_M(1, 32);
  int cur = 0, i2 = 2;
  for (int t = 0; t < nt; ++t) {
    if (t + 1 < nt) wait_vm6(); else wait_vm0();
    __builtin_amdgcn_s_barrier();
    if (t + 2 < nt) STAGE_M(i2, (t + 2) << 5);
    short8_t af[4];
    #pragma unroll
    for (int mi = 0; mi < 4; ++mi)
      af[mi] = *reinterpret_cast<const short8_t*>(&shA[cur * 4096 + (wm + (mi << 4) + lr) * 32 + rsw]);
    __builtin_amdgcn_s_setprio(1);
    #pragma unroll
    for (int ni = 0; ni < 8; ++ni) {
      short8_t bfr = *reinterpret_cast<const short8_t*>(&shB[cur * 8192 + (wn + (ni << 4) + lr) * 32 + rsw]);
      #pragma unroll
      for (int mi = 0; mi < 4; ++mi)
        acc[mi][ni] = __builtin_amdgcn_mfma_f32_16x16x32_bf16(
            __builtin_bit_cast(bf16x8_t, af[mi]),
            __builtin_bit_cast(bf16x8_t, bfr),
            acc[mi][ni], 0, 0, 0);
    }
    __builtin_amdgcn_s_setprio(0);
    cur = (cur == 2) ? 0 : cur + 1;
    i2  = (i2 == 2) ? 0 : i2 + 1;
  }
#undef STAGE_M
  #pragma unroll
  for (int half = 0; half < 2; ++half) {
    __syncthreads();
    if ((w & 1) == half) {
      #pragma unroll
      for (int ni = 0; ni < 8; ++ni)
        #pragma unroll
        for (int mi = 0; mi < 4; ++mi)
          #pragma unroll
          for (int r = 0; r < 4; ++r)
            smem[(wm + (mi << 4) + (g << 2) + r) * 136 + (ni << 4) + lr] = f2b(acc[mi][ni][r]);
    }
    __syncthreads();
    int n0e = n0 + (half << 7);
    int row = tid >> 1, halfc = (tid & 1) << 6;
    if (m0 + row < cnt_e) {
      if (SILU) {
        float scale = ewt[e * S_LEN + m0 + row];
        int ocol = (n0e >> 1) + (halfc >> 1);
        #pragma unroll
        for (int j = 0; j < 4; ++j) {
          short8_t v0 = *reinterpret_cast<const short8_t*>(&smem[row * 136 + halfc + (j << 4)]);
          short8_t v1 = *reinterpret_cast<const short8_t*>(&smem[row * 136 + halfc + (j << 4) + 8]);
          short8_t o;
          #pragma unroll
          for (int q = 0; q < 4; ++q) {
            float x = b2f(v0[2 * q]);
            o[q] = f2b((x / (1.0f + expf(-x))) * b2f(v0[2 * q + 1]) * scale);
            float y = b2f(v1[2 * q]);
            o[4 + q] = f2b((y / (1.0f + expf(-y))) * b2f(v1[2 * q + 1]) * scale);
          }
          *reinterpret_cast<short8_t*>(&Cb[(long long)(m0 + row) * ldc + ocol + (j << 3)]) = o;
        }
      } else {
        #pragma unroll
        for (int j = 0; j < 8; ++j) {
          int col = n0e + halfc + (j << 3);
          short8_t v = *reinterpret_cast<const short8_t*>(&smem[row * 136 + halfc + (j << 3)]);
          *reinterpret_cast<short8_t*>(&Cb[(long long)(m0 + row) * ldc + col]) = v;
        }
      }
    }
  }
}

// ---------------- flash attention, QBLK=64 (2 blocks/CU) ----------------
__global__ void __launch_bounds__(256)
flash_kernel(const short* __restrict__ qf, const short* __restrict__ kf,
             const short* __restrict__ vT, short* __restrict__ ao, float scale)
{
  __shared__ short smem[37888];
  const int tid = threadIdx.x;
  const int h = blockIdx.y;
  const int q0 = blockIdx.x << 6;
  const int w = tid >> 6, lane = tid & 63;
  const int lr = lane & 15, g = lane >> 4;
  const int rb = w << 4;
  const int srow = lane >> 2;
  const int sunit = ((lane & 3) ^ ((lane >> 3) & 3)) << 3;
  const int rsw = ((g ^ ((lr >> 1) & 3)) << 3);
  const short* qh = qf + (long long)h * S_LEN * DQK_;
  const short* kh = kf + (long long)h * S_LEN * DQK_;
  const short* vh = vT + (long long)h * 128 * S_LEN;

  #pragma unroll
  for (int i = 0; i < 6; ++i) {
    int c = tid + (i << 8);
    int row = c / 24, cc = c % 24;
    int dchunk = (cc & ~3) | ((cc & 3) ^ ((row >> 1) & 3));
    *reinterpret_cast<short8_t*>(&smem[row * 200 + (dchunk << 3)]) =
        *reinterpret_cast<const short8_t*>(qh + (long long)(q0 + row) * DQK_ + (cc << 3));
  }

  const f32x4 vzero = {0.f, 0.f, 0.f, 0.f};
  f32x4 oacc[8];
  #pragma unroll
  for (int ni = 0; ni < 8; ++ni) oacc[ni] = vzero;
  float mrow[4], lrow[4];
  #pragma unroll
  for (int rr = 0; rr < 4; ++rr) { mrow[rr] = -3e38f; lrow[rr] = 0.f; }

  __syncthreads();

  for (int kt = 0; kt < 16; ++kt) {
    const short* kbase = kh + (long long)(kt << 7) * DQK_;
    f32x4 sacc[8];
    #pragma unroll
    for (int ni = 0; ni < 8; ++ni) sacc[ni] = vzero;
#define STAGE_K(bi, kk) do { \
    _Pragma("unroll") \
    for (int r = 0; r < 2; ++r) { \
      int rowb = (w << 4) + (r << 6); \
      gload16(kbase + (long long)(rowb + srow) * DQK_ + (kk) * 32 + sunit, \
              &smem[12800 + (bi) * 4096 + rowb * 32]); \
    } } while (0)
    STAGE_K(0, 0);
    for (int ks = 0; ks < 6; ++ks) {
      if (ks < 5) { STAGE_K((ks + 1) & 1, ks + 1); wait_vm2(); }
      else wait_vm0();
      __builtin_amdgcn_s_barrier();
      const int kb = 12800 + (ks & 1) * 4096;
      short8_t aq = *reinterpret_cast<const short8_t*>(
          &smem[(rb + lr) * 200 + ks * 32 + rsw]);
      __builtin_amdgcn_s_setprio(1);
      #pragma unroll
      for (int ni = 0; ni < 8; ++ni) {
        short8_t bk = *reinterpret_cast<const short8_t*>(&smem[kb + ((ni << 4) + lr) * 32 + rsw]);
        sacc[ni] = __builtin_amdgcn_mfma_f32_16x16x32_bf16(
            __builtin_bit_cast(bf16x8_t, aq),
            __builtin_bit_cast(bf16x8_t, bk),
            sacc[ni], 0, 0, 0);
      }
      __builtin_amdgcn_s_setprio(0);
      __builtin_amdgcn_s_barrier();
    }
#undef STAGE_K
    #pragma unroll
    for (int rr = 0; rr < 4; ++rr) {
      float sv[8];
      float mx = -3e38f;
      #pragma unroll
      for (int ni = 0; ni < 8; ++ni) {
        sv[ni] = b2f(f2b(sacc[ni][rr])) * scale;
        mx = fmaxf(mx, sv[ni]);
      }
      #pragma unroll
      for (int d = 1; d < 16; d <<= 1) mx = fmaxf(mx, __shfl_xor(mx, d, 64));
      float mnew = fmaxf(mrow[rr], mx);
      float corr = expf(mrow[rr] - mnew);
      float psum = 0.f;
      short pb[8];
      #pragma unroll
      for (int ni = 0; ni < 8; ++ni) {
        float p = expf(sv[ni] - mnew);
        pb[ni] = f2b(p);
        psum += p;
      }
      #pragma unroll
      for (int d = 1; d < 16; d <<= 1) psum += __shfl_xor(psum, d, 64);
      lrow[rr] = lrow[rr] * corr + psum;
      mrow[rr] = mnew;
      int row = rb + (g << 2) + rr;
      int xr = (row >> 1) & 3;
      #pragma unroll
      for (int ni = 0; ni < 8; ++ni) {
        int cc = (ni << 4) + lr;
        int scc = (cc & ~31) | (((((cc >> 3) & 3) ^ xr)) << 3) | (cc & 7);
        smem[20992 + row * 136 + scc] = pb[ni];
      }
      #pragma unroll
      for (int ni = 0; ni < 8; ++ni) oacc[ni][rr] *= corr;
    }
    __syncthreads();
    const short* vbase = vh + (kt << 7);
#define STAGE_V(bi, kk) do { \
    _Pragma("unroll") \
    for (int r = 0; r < 2; ++r) { \
      int rowb = (w << 4) + (r << 6); \
      gload16(vbase + (long long)(rowb + srow) * S_LEN + (kk) * 32 + sunit, \
              &smem[29696 + (bi) * 4096 + rowb * 32]); \
    } } while (0)
    STAGE_V(0, 0);
    for (int ks = 0; ks < 4; ++ks) {
      if (ks < 3) { STAGE_V((ks + 1) & 1, ks + 1); wait_vm2(); }
      else wait_vm0();
      __builtin_amdgcn_s_barrier();
      const int vb = 29696 + (ks & 1) * 4096;
      short8_t ap = *reinterpret_cast<const short8_t*>(
          &smem[20992 + (rb + lr) * 136 + ks * 32 + rsw]);
      __builtin_amdgcn_s_setprio(1);
      #pragma unroll
      for (int ni = 0; ni < 8; ++ni) {
        short8_t bv = *reinterpret_cast<const short8_t*>(&smem[vb + ((ni << 4) + lr) * 32 + rsw]);
        oacc[ni] = __builtin_amdgcn_mfma_f32_16x16x32_bf16(
            __builtin_bit_cast(bf16x8_t, ap),
            __builtin_bit_cast(bf16x8_t, bv),
            oacc[ni], 0, 0, 0);
      }
      __builtin_amdgcn_s_setprio(0);
      __builtin_amdgcn_s_barrier();
    }
#undef STAGE_V
  }
  __syncthreads();
  #pragma unroll
  for (int ni = 0; ni < 8; ++ni)
    #pragma unroll
    for (int rr = 0; rr < 4; ++rr) {
      int row = rb + (g << 2) + rr;
      smem[20992 + row * 136 + (ni << 4) + lr] = f2b(oacc[ni][rr] / lrow[rr]);
    }
  __syncthreads();
  {
    int row = tid >> 2, quarter = (tid & 3) << 5;
    #pragma unroll
    for (int j = 0; j < 4; ++j) {
      int col = quarter + (j << 3);
      short8_t v = *reinterpret_cast<const short8_t*>(&smem[20992 + row * 136 + col]);
      *reinterpret_cast<short8_t*>(&ao[(long long)(q0 + row) * HDIM + (h << 7) + col]) = v;
    }
  }
}

// ---------------- small kernels ----------------
__global__ void __launch_bounds__(64)
rope_tables_kernel(float* cosT, float* sinT) {
  int s = blockIdx.x, j = threadIdx.x;
  int i = j & 31;
  float inv = powf(10000.0f, -((float)(2 * i) / 64.0f));
  float ang = (float)s * inv;
  cosT[s * 64 + j] = cosf(ang);
  sinT[s * 64 + j] = sinf(ang);
}

__global__ void __launch_bounds__(256)
rmsnorm_bf16_kernel(const short* __restrict__ in, long long istride,
                    const short* __restrict__ w,
                    short* __restrict__ out, long long ostride, int D) {
  const short* x = in + (long long)blockIdx.x * istride;
  short* o = out + (long long)blockIdx.x * ostride;
  const int nc = D >> 3;
  float ss = 0.f;
  for (int c = threadIdx.x; c < nc; c += 256) {
    short8_t v = reinterpret_cast<const short8_t*>(x)[c];
    #pragma unroll
    for (int j = 0; j < 8; ++j) { float f = b2f(v[j]); ss += f * f; }
  }
  __shared__ float red[256];
  red[threadIdx.x] = ss; __syncthreads();
  for (int s2 = 128; s2 > 0; s2 >>= 1) {
    if (threadIdx.x < s2) red[threadIdx.x] += red[threadIdx.x + s2];
    __syncthreads();
  }
  float r = 1.0f / sqrtf(red[0] / (float)D + 1e-6f);
  for (int c = threadIdx.x; c < nc; c += 256) {
    short8_t v = reinterpret_cast<const short8_t*>(x)[c];
    short8_t wv = reinterpret_cast<const short8_t*>(w)[c];
    short8_t ov;
    #pragma unroll
    for (int j = 0; j < 8; ++j) ov[j] = f2b(b2f(wv[j]) * (b2f(v[j]) * r));
    reinterpret_cast<short8_t*>(o)[c] = ov;
  }
}

__global__ void __launch_bounds__(256)
build_qf_kernel(const short* q, const float* cosT, const float* sinT, short* qf) {
  int s = blockIdx.x;
  for (int idx = threadIdx.x; idx < NH_ * DQK_; idx += 256) {
    int h = idx / DQK_, d = idx - h * DQK_;
    const short* qr = q + (long long)s * QN_ + h * DQK_;
    float val;
    if (d < 128) val = b2f(qr[d]);
    else {
      int j = d - 128;
      float c = cosT[s * 64 + j], sn = sinT[s * 64 + j];
      float x0 = b2f(qr[128 + j]);
      float rot = (j < 32) ? -b2f(qr[128 + j + 32]) : b2f(qr[128 + j - 32]);
      val = x0 * c + rot * sn;
    }
    qf[(long long)h * S_LEN * DQK_ + (long long)s * DQK_ + d] = f2b(val);
  }
}

__global__ void __launch_bounds__(256)
build_kf_kernel(const short* kvup, const short* krope, long long kstride,
                const float* cosT, const float* sinT, short* kf) {
  int s = blockIdx.x;
  for (int idx = threadIdx.x; idx < NH_ * DQK_; idx += 256) {
    int h = idx / DQK_, d = idx - h * DQK_;
    float val;
    if (d < 128) val = b2f(kvup[(long long)s * KVUPN + h * 256 + d]);
    else {
      int j = d - 128;
      float c = cosT[s * 64 + j], sn = sinT[s * 64 + j];
      const short* kr = krope + (long long)s * kstride;
      float x0 = b2f(kr[j]);
      float rot = (j < 32) ? -b2f(kr[j + 32]) : b2f(kr[j - 32]);
      val = x0 * c + rot * sn;
    }
    kf[(long long)h * S_LEN * DQK_ + (long long)s * DQK_ + d] = f2b(val);
  }
}

__global__ void __launch_bounds__(256)
transpose_v_kernel(const short* kvup, short* vT) {
  int h = blockIdx.z;
  int r0 = blockIdx.y * 32, c0 = blockIdx.x * 32;
  int tx = threadIdx.x & 31, ty = threadIdx.x >> 5;
  __shared__ short tile[32][33];
  #pragma unroll
  for (int i = 0; i < 4; ++i)
    tile[ty + i * 8][tx] =
        kvup[(long long)(r0 + ty + i * 8) * KVUPN + h * 256 + 128 + c0 + tx];
  __syncthreads();
  short* d = vT + (long long)h * 128 * S_LEN;
  #pragma unroll
  for (int i = 0; i < 4; ++i)
    d[(long long)(c0 + ty + i * 8) * S_LEN + r0 + tx] = tile[tx][ty + i * 8];
}

__global__ void __launch_bounds__(256)
gate_kernel(const short* x2, const short* gw, int* cnt, int* elist, float* ewt, int* tok2slot) {
  int t = blockIdx.x;
  int e = threadIdx.x >> 5, j = threadIdx.x & 31;
  const short* x = x2 + (long long)t * HDIM;
  float acc = 0.f;
  for (int k = j; k < HDIM; k += 32) acc += b2f(x[k]) * b2f(gw[(long long)k * EXP_ + e]);
  __shared__ float red[8][32];
  red[e][j] = acc; __syncthreads();
  for (int s2 = 16; s2 > 0; s2 >>= 1) {
    if (j < s2) red[e][j] += red[e][j + s2];
    __syncthreads();
  }
  if (threadIdx.x == 0) {
    float l[8], p[8];
    float m = -1e30f;
    for (int q = 0; q < 8; ++q) { l[q] = b2f(f2b(red[q][0])); m = fmaxf(m, l[q]); }
    float sum = 0.f;
    for (int q = 0; q < 8; ++q) { p[q] = expf(l[q] - m); sum += p[q]; }
    int i0 = 0; for (int q = 1; q < 8; ++q) if (p[q] > p[i0]) i0 = q;
    int i1 = (i0 == 0) ? 1 : 0;
    for (int q = 0; q < 8; ++q) if (q != i0 && p[q] > p[i1]) i1 = q;
    float denom = p[i0] + p[i1];
    float w0 = b2f(f2b(p[i0] / denom));
    float w1 = b2f(f2b(p[i1] / denom));
    int pos0 = atomicAdd(&cnt[i0], 1);
    int pos1 = atomicAdd(&cnt[i1], 1);
    elist[i0 * S_LEN + pos0] = t;  ewt[i0 * S_LEN + pos0] = w0;
    elist[i1 * S_LEN + pos1] = t;  ewt[i1 * S_LEN + pos1] = w1;
    int4* slot = (int4*)tok2slot;
    slot[t] = make_int4(i0, pos0, i1, pos1);
  }
}

__global__ void __launch_bounds__(256)
moe_combine_kernel(short* h, const short* shared_out, const short* routed,
                   const int* tok2slot) {
  int t = blockIdx.x;
  const int4 sl = ((const int4*)tok2slot)[t];
  const short8_t* s0 = reinterpret_cast<const short8_t*>(shared_out + (long long)t * HDIM);
  const short8_t* s1 = reinterpret_cast<const short8_t*>(shared_out + ((long long)S_LEN + t) * HDIM);
  const short8_t* r0 = reinterpret_cast<const short8_t*>(
      routed + ((long long)sl.x * S_LEN + sl.y) * HDIM);
  const short8_t* r1 = reinterpret_cast<const short8_t*>(
      routed + ((long long)sl.z * S_LEN + sl.w) * HDIM);
  long long c = (long long)t * 256 + threadIdx.x;
  short8_t hv = reinterpret_cast<short8_t*>(h)[c];
  short8_t a0 = s0[threadIdx.x], a1 = s1[threadIdx.x];
  short8_t v0 = r0[threadIdx.x], v1 = r1[threadIdx.x];
  short8_t ov;
  #pragma unroll
  for (int j = 0; j < 8; ++j)
    ov[j] = f2b(b2f(hv[j]) + (b2f(a0[j]) + b2f(a1[j]) + b2f(v0[j]) + b2f(v1[j])));
  reinterpret_cast<short8_t*>(h)[c] = ov;
}

// ---------------- pooling ----------------
template<int AF32, int OUTBF16>
__global__ void __launch_bounds__(256)
gemv_bt_kernel(const void* a, const short* __restrict__ BT, void* out, int K) {
  int n = blockIdx.x;
  const short8_t* row = reinterpret_cast<const short8_t*>(BT + (long long)n * K);
  float acc = 0.f;
  for (int c = threadIdx.x; c < (K >> 3); c += 256) {
    short8_t v = row[c];
    if (AF32) {
      f32x4 a0 = reinterpret_cast<const f32x4*>(a)[2 * c];
      f32x4 a1 = reinterpret_cast<const f32x4*>(a)[2 * c + 1];
      #pragma unroll
      for (int j = 0; j < 4; ++j) {
        acc += a0[j] * b2f(v[j]);
        acc += a1[j] * b2f(v[4 + j]);
      }
    } else {
      short8_t av = reinterpret_cast<const short8_t*>(a)[c];
      #pragma unroll
      for (int j = 0; j < 8; ++j) acc += b2f(av[j]) * b2f(v[j]);
    }
  }
  __shared__ float red[256];
  red[threadIdx.x] = acc; __syncthreads();
  for (int s2 = 128; s2 > 0; s2 >>= 1) {
    if (threadIdx.x < s2) red[threadIdx.x] += red[threadIdx.x + s2];
    __syncthreads();
  }
  if (threadIdx.x == 0) {
    if (OUTBF16) ((short*)out)[n] = f2b(red[0]);
    else         ((float*)out)[n] = red[0];
  }
}

__global__ void __launch_bounds__(256)
pool_score_kernel(const short* qv, const short* kmat, float* score) {
  int s = blockIdx.x;
  const short8_t* kr = reinterpret_cast<const short8_t*>(kmat + (long long)s * HDIM);
  const short8_t* qr = reinterpret_cast<const short8_t*>(qv);
  short8_t kv8 = kr[threadIdx.x], qv8 = qr[threadIdx.x];
  float acc = 0.f;
  #pragma unroll
  for (int j = 0; j < 8; ++j) acc += b2f(qv8[j]) * b2f(kv8[j]);
  __shared__ float red[256];
  red[threadIdx.x] = acc; __syncthreads();
  for (int s2 = 128; s2 > 0; s2 >>= 1) {
    if (threadIdx.x < s2) red[threadIdx.x] += red[threadIdx.x + s2];
    __syncthreads();
  }
  if (threadIdx.x == 0) score[s] = b2f(f2b(red[0])) * 0.022097086912079608f;
}

__global__ void __launch_bounds__(256)
softmax_vec_kernel(float* v) {
  int tid = threadIdx.x;
  float f[8]; float m = -1e30f;
  #pragma unroll
  for (int i = 0; i < 8; ++i) { f[i] = v[i * 256 + tid]; m = fmaxf(m, f[i]); }
  __shared__ float red[256];
  red[tid] = m; __syncthreads();
  for (int s2 = 128; s2 > 0; s2 >>= 1) {
    if (tid < s2) red[tid] = fmaxf(red[tid], red[tid + s2]);
    __syncthreads();
  }
  m = red[0]; __syncthreads();
  float sum = 0.f;
  #pragma unroll
  for (int i = 0; i < 8; ++i) { f[i] = expf(f[i] - m); sum += f[i]; }
  red[tid] = sum; __syncthreads();
  for (int s2 = 128; s2 > 0; s2 >>= 1) {
    if (tid < s2) red[tid] += red[tid + s2];
    __syncthreads();
  }
  float inv = 1.0f / red[0];
  #pragma unroll
  for (int i = 0; i < 8; ++i) v[i * 256 + tid] = f[i] * inv;
}

__global__ void __launch_bounds__(256)
pool_wsum_t_kernel(const float* w, const short* vT, float* pooled) {
  int h = blockIdx.x;
  const short8_t* row = reinterpret_cast<const short8_t*>(vT + (long long)h * S_LEN);
  int c = threadIdx.x;
  short8_t v = row[c];
  f32x4 w0 = reinterpret_cast<const f32x4*>(w)[2 * c];
  f32x4 w1 = reinterpret_cast<const f32x4*>(w)[2 * c + 1];
  float acc = 0.f;
  #pragma unroll
  for (int j = 0; j < 4; ++j) {
    acc += w0[j] * b2f(v[j]);
    acc += w1[j] * b2f(v[4 + j]);
  }
  __shared__ float red[256];
  red[threadIdx.x] = acc; __syncthreads();
  for (int s2 = 128; s2 > 0; s2 >>= 1) {
    if (threadIdx.x < s2) red[threadIdx.x] += red[threadIdx.x + s2];
    __syncthreads();
  }
  if (threadIdx.x == 0) pooled[h] = red[0];
}

__global__ void __launch_bounds__(256)
rmsnorm_f32_kernel(const float* x, const short* w, float* out) {
  int tid = threadIdx.x;
  float f[8]; float ss = 0.f;
  #pragma unroll
  for (int i = 0; i < 8; ++i) { f[i] = x[i * 256 + tid]; ss += f[i] * f[i]; }
  __shared__ float red[256];
  red[tid] = ss; __syncthreads();
  for (int s2 = 128; s2 > 0; s2 >>= 1) {
    if (tid < s2) red[tid] += red[tid + s2];
    __syncthreads();
  }
  float r = 1.0f / sqrtf(red[0] / 2048.0f + 1e-6f);
  #pragma unroll
  for (int i = 0; i < 8; ++i) out[i * 256 + tid] = b2f(w[i * 256 + tid]) * (f[i] * r);
}

// ---------------- host ----------------
extern "C" void kernel_launch(void* const* d_in, const int* in_sizes, int n_in,
                              void* d_out, int out_size, void* d_ws, size_t ws_size,
                              hipStream_t stream)
{
  (void)n_in; (void)out_size; (void)ws_size;
  const int* ids = (const int*)d_in[24];

  char* base = (char*)d_ws;
  size_t off = 0;
  auto alloc = [&](size_t bytes) -> void* {
    void* p = base + off;
    off += (bytes + 255) & ~(size_t)255;
    return p;
  };

  int* dflag = (int*)alloc(256);

  short* qkvdwT = (short*)alloc((size_t)2 * DCAT * HDIM * 2);
  short* quwT  = (short*)alloc((size_t)2 * QN_ * QRANK_ * 2);
  short* kvuwT = (short*)alloc((size_t)2 * KVUPN * KVRANK_ * 2);
  short* opwT  = (short*)alloc((size_t)2 * HDIM * HDIM * 2);
  short* rw13T = (short*)alloc((size_t)16 * IFF2 * HDIM * 2);
  short* rw2T  = (short*)alloc((size_t)16 * HDIM * IFF_ * 2);
  short* sw13T = (short*)alloc((size_t)4 * IFF2 * HDIM * 2);
  short* sw2T  = (short*)alloc((size_t)4 * HDIM * IFF_ * 2);
  short* pqwT  = (short*)alloc((size_t)HDIM * HDIM * 2);
  short* pkwT  = (short*)alloc((size_t)HDIM * HDIM * 2);
  short* pvwT  = (short*)alloc((size_t)HDIM * HDIM * 2);
  short* powT  = (short*)alloc((size_t)PD_ * HDIM * 2);
  short* ln1w = (short*)alloc((size_t)in_sizes[1] * 2);
  short* qnw  = (short*)alloc((size_t)in_sizes[3] * 2);
  short* kvnw = (short*)alloc((size_t)in_sizes[6] * 2);
  short* ln2w = (short*)alloc((size_t)in_sizes[9] * 2);
  short* gatw = (short*)alloc((size_t)in_sizes[10] * 2);
  short* fnww = (short*)alloc((size_t)in_sizes[17] * 2);
  short* lqw  = (short*)alloc((size_t)in_sizes[18] * 2);
  short* pnww = (short*)alloc((size_t)in_sizes[23] * 2);

  float* cosT    = (float*)alloc((size_t)S_LEN * 64 * 4);
  float* sinT    = (float*)alloc((size_t)S_LEN * 64 * 4);
  short* hbuf    = (short*)alloc((size_t)S_LEN * HDIM * 2);
  short* xbuf    = (short*)alloc((size_t)S_LEN * HDIM * 2);
  short* dcat    = (short*)alloc((size_t)S_LEN * DCAT * 2);
  short* qlatn   = (short*)alloc((size_t)S_LEN * QRANK_ * 2);
  short* qbuf    = (short*)alloc((size_t)S_LEN * QN_ * 2);
  short* kvn     = (short*)alloc((size_t)S_LEN * KVRANK_ * 2);
  short* kvup    = (short*)alloc((size_t)S_LEN * KVUPN * 2);
  short* qf      = (short*)alloc((size_t)NH_ * S_LEN * DQK_ * 2);
  short* kf      = (short*)alloc((size_t)NH_ * S_LEN * DQK_ * 2);
  short* vT      = (short*)alloc((size_t)NH_ * 128 * S_LEN * 2);
  short* ao      = (short*)alloc((size_t)S_LEN * HDIM * 2);
  short* hfin    = (short*)alloc((size_t)S_LEN * HDIM * 2);
  short* kpool   = (short*)alloc((size_t)S_LEN * HDIM * 2);
  short* vpoolT  = (short*)alloc((size_t)HDIM * S_LEN * 2);
  short* qvec    = (short*)alloc((size_t)HDIM * 2);
  float* pscore  = (float*)alloc((size_t)S_LEN * 4);
  float* pooled  = (float*)alloc((size_t)HDIM * 4);
  float* pooledn = (float*)alloc((size_t)HDIM * 4);
  int*   ecnt    = (int*)alloc(64);
  int*   elist   = (int*)alloc((size_t)EXP_ * S_LEN * 4);
  float* ewt     = (float*)alloc((size_t)EXP_ * S_LEN * 4);
  int*   tok2slot= (int*)alloc((size_t)S_LEN * 16);
  short* gba_e   = (short*)alloc((size_t)EXP_ * S_LEN * IFF_ * 2);
  short* routed  = (short*)alloc((size_t)EXP_ * S_LEN * HDIM * 2);
  short* gsh1    = (short*)alloc((size_t)S_LEN * IFF2 * 2);
  short* shared_out = (short*)alloc((size_t)2 * S_LEN * HDIM * 2);

  detect_kernel<<<1, 256, 0, stream>>>(d_in[0], dflag);

  auto tconv = [&](const void* src, short* dst, int R, int C, int nslabs,
                   long long sSrc, long long sDst, int rowMul, int rowOff) {
    dim3 grid(C / 32, R / 32, nslabs);
    transconv_kernel<<<grid, 256, 0, stream>>>(src, dst, R, C, dflag, sSrc, sDst, rowMul, rowOff);
  };
  auto pconv = [&](const void* src, short* dst, long long n) {
    long long nchunks = n / 8;
    int blocks = (int)((nchunks + 255) / 256);
    if (blocks > 2048) blocks = 2048;
    if (blocks < 1) blocks = 1;
    convert_kernel<<<blocks, 256, 0, stream>>>(src, dst, nchunks, dflag);
  };

  tconv(d_in[2], qkvdwT, HDIM, QRANK_, 2,
        (long long)HDIM * QRANK_, (long long)DCAT * HDIM, 1, 0);
  tconv(d_in[5], qkvdwT + (size_t)QRANK_ * HDIM, HDIM, KVDN, 2,
        (long long)HDIM * KVDN, (long long)DCAT * HDIM, 1, 0);
  tconv(d_in[4],  quwT,  QRANK_, QN_,  2, (long long)QRANK_ * QN_,  (long long)QN_ * QRANK_, 1, 0);
  tconv(d_in[7],  kvuwT, KVRANK_,KVUPN,2, (long long)KVRANK_ * KVUPN,(long long)KVUPN * KVRANK_, 1, 0);
  tconv(d_in[8],  opwT,  HDIM,   HDIM, 2, (long long)HDIM * HDIM,   (long long)HDIM * HDIM, 1, 0);
  tconv(d_in[11], rw13T, HDIM,   IFF_, 16,(long long)HDIM * IFF_,   (long long)IFF2 * HDIM, 2, 0);
  tconv(d_in[13], rw13T, HDIM,   IFF_, 16,(long long)HDIM * IFF_,   (long long)IFF2 * HDIM, 2, 1);
  tconv(d_in[12], rw2T,  IFF_,   HDIM, 16,(long long)IFF_ * HDIM,   (long long)HDIM * IFF_, 1, 0);
  tconv(d_in[14], sw13T, HDIM,   IFF_, 4, (long long)HDIM * IFF_,   (long long)IFF2 * HDIM, 2, 0);
  tconv(d_in[16], sw13T, HDIM,   IFF_, 4, (long long)HDIM * IFF_,   (long long)IFF2 * HDIM, 2, 1);
  tconv(d_in[15], sw2T,  IFF_,   HDIM, 4, (long long)IFF_ * HDIM,   (long long)HDIM * IFF_, 1, 0);
  tconv(d_in[19], pqwT,  HDIM,   HDIM, 1, 0, 0, 1, 0);
  tconv(d_in[20], pkwT,  HDIM,   HDIM, 1, 0, 0, 1, 0);
  tconv(d_in[21], pvwT,  HDIM,   HDIM, 1, 0, 0, 1, 0);
  tconv(d_in[22], powT,  HDIM,   PD_,  1, 0, 0, 1, 0);
  pconv(d_in[1],  ln1w, in_sizes[1]);
  pconv(d_in[3],  qnw,  in_sizes[3]);
  pconv(d_in[6],  kvnw, in_sizes[6]);
  pconv(d_in[9],  ln2w, in_sizes[9]);
  pconv(d_in[10], gatw, in_sizes[10]);
  pconv(d_in[17], fnww, in_sizes[17]);
  pconv(d_in[18], lqw,  in_sizes[18]);
  pconv(d_in[23], pnww, in_sizes[23]);

  const float qk_scale = 1.0f / sqrtf((float)DQK_);

  auto gemm = [&](int epi, const short* A, const short* B, short* C,
                  int M, int N, int K, int lda, int ldb, int ldc,
                  int batch, long long sA, long long sB, long long sC) {
    dim3 grid(M / 128, (N + 255) / 256, batch);
    if (epi == 0)
      gemm_kernel<0><<<grid, 256, 0, stream>>>(A, B, C, M, N, K, lda, ldb, ldc, sA, sB, sC);
    else if (epi == 1)
      gemm_kernel<1><<<grid, 256, 0, stream>>>(A, B, C, M, N, K, lda, ldb, ldc, sA, sB, sC);
    else
      gemm_kernel<2><<<grid, 256, 0, stream>>>(A, B, C, M, N, K, lda, ldb, ldc, sA, sB, sC);
  };

  rope_tables_kernel<<<S_LEN, 64, 0, stream>>>(cosT, sinT);
  embed_convert_kernel<<<S_LEN, 256, 0, stream>>>(ids, d_in[0], dflag, hbuf);

  for (int l = 0; l < 2; ++l) {
    const short* w_ln1  = ln1w + (size_t)l * HDIM;
    const short* w_qkvT = qkvdwT + (size_t)l * DCAT * HDIM;
    const short* w_qn   = qnw  + (size_t)l * QRANK_;
    const short* w_quT  = quwT + (size_t)l * QN_ * QRANK_;
    const short* w_kvn  = kvnw + (size_t)l * KVRANK_;
    const short* w_kvuT = kvuwT+ (size_t)l * KVUPN * KVRANK_;
    const short* w_opT  = opwT + (size_t)l * HDIM * HDIM;
    const short* w_ln2  = ln2w + (size_t)l * HDIM;
    const short* w_gat  = gatw + (size_t)l * HDIM * EXP_;

    // --- attention ---
    rmsnorm_bf16_kernel<<<S_LEN, 256, 0, stream>>>(hbuf, HDIM, w_ln1, xbuf, HDIM, HDIM);
    gemm(0, xbuf, w_qkvT, dcat, S_LEN, DCAT, HDIM, HDIM, HDIM, DCAT, 1, 0, 0, 0);
    rmsnorm_bf16_kernel<<<S_LEN, 256, 0, stream>>>(dcat, DCAT, w_qn, qlatn, QRANK_, QRANK_);
    gemm(0, qlatn, w_quT, qbuf, S_LEN, QN_, QRANK_, QRANK_, QRANK_, QN_, 1, 0, 0, 0);
    rmsnorm_bf16_kernel<<<S_LEN, 256, 0, stream>>>(dcat + QRANK_, DCAT, w_kvn, kvn, KVRANK_, KVRANK_);
    gemm(0, kvn, w_kvuT, kvup, S_LEN, KVUPN, KVRANK_, KVRANK_, KVRANK_, KVUPN, 1, 0, 0, 0);
    build_qf_kernel<<<S_LEN, 256, 0, stream>>>(qbuf, cosT, sinT, qf);
    build_kf_kernel<<<S_LEN, 256, 0, stream>>>(kvup, dcat + QRANK_ + KVRANK_, DCAT, cosT, sinT, kf);
    {
      dim3 tg(128 / 32, S_LEN / 32, NH_);
      transpose_v_kernel<<<tg, 256, 0, stream>>>(kvup, vT);
    }
    {
      dim3 fg(S_LEN / 64, NH_);
      flash_kernel<<<fg, 256, 0, stream>>>(qf, kf, vT, ao, qk_scale);
    }
    gemm(2, ao, w_opT, hbuf, S_LEN, HDIM, HDIM, HDIM, HDIM, HDIM, 1, 0, 0, 0);

    // --- MoE ---
    rmsnorm_bf16_kernel<<<S_LEN, 256, 0, stream>>>(hbuf, HDIM, w_ln2, xbuf, HDIM, HDIM);
    hipMemsetAsync(ecnt, 0, 64, stream);
    gate_kernel<<<S_LEN, 256, 0, stream>>>(xbuf, w_gat, ecnt, elist, ewt, tok2slot);
    {
      const short* a13 = sw13T + (size_t)l * 2 * IFF2 * HDIM;
      const short* a2  = sw2T  + (size_t)l * 2 * HDIM * IFF_;
      gemm(1, xbuf, a13, gsh1, S_LEN, 2 * IFF2, HDIM, HDIM, HDIM, IFF2, 1, 0, 0, 0);
      gemm(0, gsh1, a2, shared_out, S_LEN, HDIM, IFF_, IFF2, IFF_, HDIM, 2,
           (long long)IFF_, (long long)HDIM * IFF_, (long long)S_LEN * HDIM);
    }
    {
      const short* b13 = rw13T + (size_t)l * 8 * IFF2 * HDIM;
      const short* b2  = rw2T  + (size_t)l * 8 * HDIM * IFF_;
      dim3 g13((IFF2 + 255) / 256, S_LEN / 128, EXP_);
      moe_gemm_kernel<1, 1><<<g13, 256, 0, stream>>>(
          xbuf, elist, ecnt, b13, gba_e, ewt, IFF2, HDIM, HDIM, HDIM, IFF_,
          0, (long long)IFF2 * HDIM, (long long)S_LEN * IFF_);
      dim3 g2(HDIM / 256, S_LEN / 128, EXP_);
      moe_gemm_kernel<0, 0><<<g2, 256, 0, stream>>>(
          gba_e, elist, ecnt, b2, routed, nullptr, HDIM, IFF_, IFF_, IFF_, HDIM,
          (long long)S_LEN * IFF_, (long long)HDIM * IFF_, (long long)S_LEN * HDIM);
      moe_combine_kernel<<<S_LEN, 256, 0, stream>>>(hbuf, shared_out, routed, tok2slot);
    }
  }

  // --- attention pooling head ---
  rmsnorm_bf16_kernel<<<S_LEN, 256, 0, stream>>>(hbuf, HDIM, fnww, hfin, HDIM, HDIM);
  gemm(0, hfin, pkwT, kpool, S_LEN, HDIM, HDIM, HDIM, HDIM, HDIM, 1, 0, 0, 0);
  gemm(0, pvwT, hfin, vpoolT, HDIM, S_LEN, HDIM, HDIM, HDIM, S_LEN, 1, 0, 0, 0);
  gemv_bt_kernel<0,1><<<HDIM, 256, 0, stream>>>(lqw, pqwT, qvec, HDIM);
  pool_score_kernel<<<S_LEN, 256, 0, stream>>>(qvec, kpool, pscore);
  softmax_vec_kernel<<<1, 256, 0, stream>>>(pscore);
  pool_wsum_t_kernel<<<HDIM, 256, 0, stream>>>(pscore, vpoolT, pooled);
  rmsnorm_f32_kernel<<<1, 256, 0, stream>>>(pooled, pnww, pooledn);
  gemv_bt_kernel<1,0><<<PD_, 256, 0, stream>>>(pooledn, powT, (float*)d_out, HDIM);
}

// Round 14
// 1622.597 us; speedup vs baseline: 1.0773x; 1.0773x over previous
//
#include <hip/hip_runtime.h>
#include <hip/hip_bf16.h>

#define S_LEN  2048
#define HDIM   2048
#define NH_    16
#define DQK_   192
#define QRANK_ 1024
#define KVRANK_ 512
#define KVDN   576
#define DCAT   1600   // QRANK + KVDN merged down-proj width
#define KVUPN  4096
#define QN_    3072
#define IFF_   1408
#define IFF2   2816   // interleaved w1|w3 width
#define EXP_   8
#define PD_    4096

typedef __attribute__((ext_vector_type(8))) short   short8_t;
typedef __attribute__((ext_vector_type(8))) __bf16  bf16x8_t;
typedef __attribute__((ext_vector_type(4))) float   f32x4;

static __device__ __forceinline__ float b2f(short s) {
  unsigned int u = ((unsigned int)(unsigned short)s) << 16;
  return __builtin_bit_cast(float, u);
}
static __device__ __forceinline__ short f2b(float f) {
  return __builtin_bit_cast(short, __float2bfloat16(f));
}

static __device__ __forceinline__ void gload16(const void* g, void* l) {
  __builtin_amdgcn_global_load_lds(
      (const __attribute__((address_space(1))) void*)g,
      (__attribute__((address_space(3))) void*)l,
      16, 0, 0);
}
static __device__ __forceinline__ void wait_vm4() { asm volatile("s_waitcnt vmcnt(4)" ::: "memory"); }
static __device__ __forceinline__ void wait_vm2() { asm volatile("s_waitcnt vmcnt(2)" ::: "memory"); }
static __device__ __forceinline__ void wait_vm0() { asm volatile("s_waitcnt vmcnt(0)" ::: "memory"); }

// ---------------- dtype detect + convert ----------------
__global__ void __launch_bounds__(256)
detect_kernel(const void* probe, int* flag) {
  const float* f = (const float*)probe;
  int tid = threadIdx.x;
  int cnt = 0;
  for (int i = tid; i < 2048; i += 256) {
    float v = fabsf(f[i]);
    if (v > 1e-6f && v < 10.0f) cnt++;
  }
  __shared__ int red[256];
  red[tid] = cnt; __syncthreads();
  for (int s = 128; s > 0; s >>= 1) {
    if (tid < s) red[tid] += red[tid + s];
    __syncthreads();
  }
  if (tid == 0) *flag = (red[0] > 1600) ? 1 : 0;
}

__global__ void __launch_bounds__(256)
convert_kernel(const void* src, short* dst, long long nchunks, const int* flag) {
  long long idx = (long long)blockIdx.x * 256 + threadIdx.x;
  long long stride = (long long)gridDim.x * 256;
  if (*flag) {
    const f32x4* s = (const f32x4*)src;
    for (long long c = idx; c < nchunks; c += stride) {
      f32x4 a = s[2 * c], b = s[2 * c + 1];
      short8_t o;
      #pragma unroll
      for (int j = 0; j < 4; ++j) { o[j] = f2b(a[j]); o[4 + j] = f2b(b[j]); }
      reinterpret_cast<short8_t*>(dst)[c] = o;
    }
  } else {
    const short8_t* s = (const short8_t*)src;
    for (long long c = idx; c < nchunks; c += stride)
      reinterpret_cast<short8_t*>(dst)[c] = s[c];
  }
}

// transpose-convert: src slab [R][C] -> dst rows (c*rowMul+rowOff) stride R, bf16
__global__ void __launch_bounds__(256)
transconv_kernel(const void* src, short* dst, int R, int C, const int* flag,
                 long long sSrc, long long sDst, int rowMul, int rowOff) {
  long long zs = (long long)blockIdx.z * sSrc;
  long long zd = (long long)blockIdx.z * sDst;
  int r0 = blockIdx.y * 32, c0 = blockIdx.x * 32;
  int tx = threadIdx.x & 31, ty = threadIdx.x >> 5;
  __shared__ short tile[32][33];
  if (*flag) {
    const float* s = (const float*)src + zs;
    #pragma unroll
    for (int i = 0; i < 4; ++i)
      tile[ty + i * 8][tx] = f2b(s[(long long)(r0 + ty + i * 8) * C + c0 + tx]);
  } else {
    const short* s = (const short*)src + zs;
    #pragma unroll
    for (int i = 0; i < 4; ++i)
      tile[ty + i * 8][tx] = s[(long long)(r0 + ty + i * 8) * C + c0 + tx];
  }
  __syncthreads();
  short* d = dst + zd;
  #pragma unroll
  for (int i = 0; i < 4; ++i)
    d[(long long)((c0 + ty + i * 8) * rowMul + rowOff) * R + r0 + tx] = tile[tx][ty + i * 8];
}

__global__ void __launch_bounds__(256)
embed_convert_kernel(const int* ids, const void* emb, const int* flag, short* h) {
  int s = blockIdx.x;
  long long row = ids[s];
  int c = threadIdx.x;
  short8_t o;
  if (*flag) {
    const f32x4* src = (const f32x4*)((const float*)emb + row * HDIM);
    f32x4 a = src[2 * c], b = src[2 * c + 1];
    #pragma unroll
    for (int j = 0; j < 4; ++j) { o[j] = f2b(a[j]); o[4 + j] = f2b(b[j]); }
  } else {
    o = reinterpret_cast<const short8_t*>((const short*)emb + row * HDIM)[c];
  }
  reinterpret_cast<short8_t*>(h + (long long)s * HDIM)[c] = o;
}

// ---------------- pipelined MFMA GEMM, 128x128 tile (B always [N][K], bf16 C) ----------------
// GRID: (n_tiles, m_tiles, batch) — n fastest so B-panels are XCD-local when n_tiles%8==0.
// EPI=0: plain store. EPI=1: fused SiLU-pair (even=gate, odd=up), writes N/2 cols. EPI=2: in-place add.
template<int EPI>
__global__ void __launch_bounds__(256)
gemm_kernel(const short* __restrict__ A, const short* __restrict__ B,
            short* __restrict__ Cv, int M, int N, int K,
            int lda, int ldb, int ldc,
            long long sAb, long long sBb, long long sCb)
{
  __shared__ short smem[24576];
  short* shA = smem;
  short* shB = smem + 12288;
  const int tid = threadIdx.x;
  const long long bz = blockIdx.z;
  const short* Ab = A + bz * sAb;
  const short* Bb = B + bz * sBb;
  const int m0 = blockIdx.y * 128;
  const int n0 = blockIdx.x * 128;
  const int w = tid >> 6, lane = tid & 63;
  const int wm = (w >> 1) << 6, wn = (w & 1) << 6;
  const int lr = lane & 15, g = lane >> 4;
  const int srow = lane >> 2;
  const int sunit = ((lane & 3) ^ ((lane >> 3) & 3)) << 3;
  const int rsw = ((g ^ ((lr >> 1) & 3)) << 3);
  const f32x4 vzero = {0.f, 0.f, 0.f, 0.f};
  f32x4 acc[4][4];
  #pragma unroll
  for (int i = 0; i < 4; ++i)
    #pragma unroll
    for (int j = 0; j < 4; ++j) acc[i][j] = vzero;

  const int nt = K >> 5;
#define STAGE_G(bi, kk) do { \
    _Pragma("unroll") \
    for (int r = 0; r < 2; ++r) { \
      int rowb = (w << 4) + (r << 6); \
      gload16(Ab + (long long)(m0 + rowb + srow) * lda + (kk) + sunit, &shA[(bi) * 4096 + rowb * 32]); \
      gload16(Bb + (long long)(n0 + rowb + srow) * ldb + (kk) + sunit, &shB[(bi) * 4096 + rowb * 32]); \
    } } while (0)

  STAGE_G(0, 0);
  if (nt > 1) STAGE_G(1, 32);
  int cur = 0, i2 = 2;
  for (int t = 0; t < nt; ++t) {
    if (t + 1 < nt) wait_vm4(); else wait_vm0();
    __builtin_amdgcn_s_barrier();
    if (t + 2 < nt) STAGE_G(i2, (t + 2) << 5);
    short8_t af[4];
    #pragma unroll
    for (int mi = 0; mi < 4; ++mi)
      af[mi] = *reinterpret_cast<const short8_t*>(&shA[cur * 4096 + (wm + (mi << 4) + lr) * 32 + rsw]);
    __builtin_amdgcn_s_setprio(1);
    #pragma unroll
    for (int ni = 0; ni < 4; ++ni) {
      short8_t bfr = *reinterpret_cast<const short8_t*>(&shB[cur * 4096 + (wn + (ni << 4) + lr) * 32 + rsw]);
      #pragma unroll
      for (int mi = 0; mi < 4; ++mi)
        acc[mi][ni] = __builtin_amdgcn_mfma_f32_16x16x32_bf16(
            __builtin_bit_cast(bf16x8_t, af[mi]),
            __builtin_bit_cast(bf16x8_t, bfr),
            acc[mi][ni], 0, 0, 0);
    }
    __builtin_amdgcn_s_setprio(0);
    cur = (cur == 2) ? 0 : cur + 1;
    i2  = (i2 == 2) ? 0 : i2 + 1;
  }
#undef STAGE_G
  __syncthreads();
  #pragma unroll
  for (int ni = 0; ni < 4; ++ni)
    #pragma unroll
    for (int mi = 0; mi < 4; ++mi)
      #pragma unroll
      for (int r = 0; r < 4; ++r)
        smem[(wm + (mi << 4) + (g << 2) + r) * 136 + wn + (ni << 4) + lr] = f2b(acc[mi][ni][r]);
  __syncthreads();
  {
    short* C = Cv + bz * sCb;
    int row = tid >> 1, half = (tid & 1) << 6;
    if (EPI == 1) {
      int ocol = (n0 >> 1) + (half >> 1);
      #pragma unroll
      for (int j = 0; j < 4; ++j) {
        short8_t v0 = *reinterpret_cast<const short8_t*>(&smem[row * 136 + half + (j << 4)]);
        short8_t v1 = *reinterpret_cast<const short8_t*>(&smem[row * 136 + half + (j << 4) + 8]);
        short8_t o;
        #pragma unroll
        for (int q = 0; q < 4; ++q) {
          float x = b2f(v0[2 * q]);
          o[q] = f2b((x / (1.0f + expf(-x))) * b2f(v0[2 * q + 1]));
          float y = b2f(v1[2 * q]);
          o[4 + q] = f2b((y / (1.0f + expf(-y))) * b2f(v1[2 * q + 1]));
        }
        *reinterpret_cast<short8_t*>(&C[(long long)(m0 + row) * ldc + ocol + (j << 3)]) = o;
      }
    } else {
      #pragma unroll
      for (int j = 0; j < 8; ++j) {
        int col = n0 + half + (j << 3);
        if (col + 8 <= N) {
          short8_t v = *reinterpret_cast<const short8_t*>(&smem[row * 136 + half + (j << 3)]);
          short* cp = &C[(long long)(m0 + row) * ldc + col];
          if (EPI == 2) {
            short8_t hv = *reinterpret_cast<const short8_t*>(cp);
            short8_t o;
            #pragma unroll
            for (int q = 0; q < 8; ++q) o[q] = f2b(b2f(hv[q]) + b2f(v[q]));
            *reinterpret_cast<short8_t*>(cp) = o;
          } else {
            *reinterpret_cast<short8_t*>(cp) = v;
          }
        }
      }
    }
  }
}

// ---------------- pipelined sparse MoE gather GEMM, 128x128 tile ----------------
// GRID: (n_tiles, m_tiles, experts) — m on Y so early-exit blocks spread across XCDs.
template<int GATHER, int SILU>
__global__ void __launch_bounds__(256)
moe_gemm_kernel(const short* __restrict__ A, const int* __restrict__ elist,
                const int* __restrict__ cnt, const short* __restrict__ B,
                short* __restrict__ C, const float* __restrict__ ewt,
                int N, int K, int lda, int ldb, int ldc,
                long long sAe, long long sBe, long long sCe)
{
  const int e = blockIdx.z;
  const int cnt_e = cnt[e];
  const int m0 = blockIdx.y << 7;
  if (m0 >= cnt_e) return;
  const short* Bb = B + (long long)e * sBe;
  short* Cb = C + (long long)e * sCe;
  const int n0 = blockIdx.x << 7;
  const int tid = threadIdx.x;
  const int w = tid >> 6, lane = tid & 63;
  const int wm = (w >> 1) << 6, wn = (w & 1) << 6;
  const int lr = lane & 15, g = lane >> 4;
  const int srow = lane >> 2;
  const int sunit = ((lane & 3) ^ ((lane >> 3) & 3)) << 3;
  const int rsw = ((g ^ ((lr >> 1) & 3)) << 3);

  long long arow[2];
  #pragma unroll
  for (int r = 0; r < 2; ++r) {
    int row = m0 + (w << 4) + (r << 6) + srow;
    if (GATHER) {
      int p = row > cnt_e - 1 ? cnt_e - 1 : row;
      arow[r] = (long long)elist[e * S_LEN + p] * lda;
    } else {
      arow[r] = (long long)e * sAe + (long long)row * lda;
    }
  }

  __shared__ short smem[24576];
  short* shA = smem;
  short* shB = smem + 12288;
  const f32x4 vzero = {0.f, 0.f, 0.f, 0.f};
  f32x4 acc[4][4];
  #pragma unroll
  for (int i = 0; i < 4; ++i)
    #pragma unroll
    for (int j = 0; j < 4; ++j) acc[i][j] = vzero;

  const int nt = K >> 5;
#define STAGE_M(bi, kk) do { \
    _Pragma("unroll") \
    for (int r = 0; r < 2; ++r) { \
      int rowb = (w << 4) + (r << 6); \
      gload16(A + arow[r] + (kk) + sunit, &shA[(bi) * 4096 + rowb * 32]); \
      gload16(Bb + (long long)(n0 + rowb + srow) * ldb + (kk) + sunit, &shB[(bi) * 4096 + rowb * 32]); \
    } } while (0)

  STAGE_M(0, 0);
  if (nt > 1) STAGE_M(1, 32);
  int cur = 0, i2 = 2;
  for (int t = 0; t < nt; ++t) {
    if (t + 1 < nt) wait_vm4(); else wait_vm0();
    __builtin_amdgcn_s_barrier();
    if (t + 2 < nt) STAGE_M(i2, (t + 2) << 5);
    short8_t af[4];
    #pragma unroll
    for (int mi = 0; mi < 4; ++mi)
      af[mi] = *reinterpret_cast<const short8_t*>(&shA[cur * 4096 + (wm + (mi << 4) + lr) * 32 + rsw]);
    __builtin_amdgcn_s_setprio(1);
    #pragma unroll
    for (int ni = 0; ni < 4; ++ni) {
      short8_t bfr = *reinterpret_cast<const short8_t*>(&shB[cur * 4096 + (wn + (ni << 4) + lr) * 32 + rsw]);
      #pragma unroll
      for (int mi = 0; mi < 4; ++mi)
        acc[mi][ni] = __builtin_amdgcn_mfma_f32_16x16x32_bf16(
            __builtin_bit_cast(bf16x8_t, af[mi]),
            __builtin_bit_cast(bf16x8_t, bfr),
            acc[mi][ni], 0, 0, 0);
    }
    __builtin_amdgcn_s_setprio(0);
    cur = (cur == 2) ? 0 : cur + 1;
    i2  = (i2 == 2) ? 0 : i2 + 1;
  }
#undef STAGE_M
  __syncthreads();
  #pragma unroll
  for (int ni = 0; ni < 4; ++ni)
    #pragma unroll
    for (int mi = 0; mi < 4; ++mi)
      #pragma unroll
      for (int r = 0; r < 4; ++r)
        smem[(wm + (mi << 4) + (g << 2) + r) * 136 + wn + (ni << 4) + lr] = f2b(acc[mi][ni][r]);
  __syncthreads();
  {
    int row = tid >> 1, half = (tid & 1) << 6;
    if (m0 + row < cnt_e) {
      if (SILU) {
        float scale = ewt[e * S_LEN + m0 + row];
        int ocol = (n0 >> 1) + (half >> 1);
        #pragma unroll
        for (int j = 0; j < 4; ++j) {
          short8_t v0 = *reinterpret_cast<const short8_t*>(&smem[row * 136 + half + (j << 4)]);
          short8_t v1 = *reinterpret_cast<const short8_t*>(&smem[row * 136 + half + (j << 4) + 8]);
          short8_t o;
          #pragma unroll
          for (int q = 0; q < 4; ++q) {
            float x = b2f(v0[2 * q]);
            o[q] = f2b((x / (1.0f + expf(-x))) * b2f(v0[2 * q + 1]) * scale);
            float y = b2f(v1[2 * q]);
            o[4 + q] = f2b((y / (1.0f + expf(-y))) * b2f(v1[2 * q + 1]) * scale);
          }
          *reinterpret_cast<short8_t*>(&Cb[(long long)(m0 + row) * ldc + ocol + (j << 3)]) = o;
        }
      } else {
        #pragma unroll
        for (int j = 0; j < 8; ++j) {
          int col = n0 + half + (j << 3);
          short8_t v = *reinterpret_cast<const short8_t*>(&smem[row * 136 + half + (j << 3)]);
          *reinterpret_cast<short8_t*>(&Cb[(long long)(m0 + row) * ldc + col]) = v;
        }
      }
    }
  }
}

// ---------------- flash attention, QBLK=64 (2 blocks/CU) ----------------
__global__ void __launch_bounds__(256)
flash_kernel(const short* __restrict__ qf, const short* __restrict__ kf,
             const short* __restrict__ vT, short* __restrict__ ao, float scale)
{
  __shared__ short smem[37888];
  const int tid = threadIdx.x;
  const int h = blockIdx.y;
  const int q0 = blockIdx.x << 6;
  const int w = tid >> 6, lane = tid & 63;
  const int lr = lane & 15, g = lane >> 4;
  const int rb = w << 4;
  const int srow = lane >> 2;
  const int sunit = ((lane & 3) ^ ((lane >> 3) & 3)) << 3;
  const int rsw = ((g ^ ((lr >> 1) & 3)) << 3);
  const short* qh = qf + (long long)h * S_LEN * DQK_;
  const short* kh = kf + (long long)h * S_LEN * DQK_;
  const short* vh = vT + (long long)h * 128 * S_LEN;

  #pragma unroll
  for (int i = 0; i < 6; ++i) {
    int c = tid + (i << 8);
    int row = c / 24, cc = c % 24;
    int dchunk = (cc & ~3) | ((cc & 3) ^ ((row >> 1) & 3));
    *reinterpret_cast<short8_t*>(&smem[row * 200 + (dchunk << 3)]) =
        *reinterpret_cast<const short8_t*>(qh + (long long)(q0 + row) * DQK_ + (cc << 3));
  }

  const f32x4 vzero = {0.f, 0.f, 0.f, 0.f};
  f32x4 oacc[8];
  #pragma unroll
  for (int ni = 0; ni < 8; ++ni) oacc[ni] = vzero;
  float mrow[4], lrow[4];
  #pragma unroll
  for (int rr = 0; rr < 4; ++rr) { mrow[rr] = -3e38f; lrow[rr] = 0.f; }

  __syncthreads();

  for (int kt = 0; kt < 16; ++kt) {
    const short* kbase = kh + (long long)(kt << 7) * DQK_;
    f32x4 sacc[8];
    #pragma unroll
    for (int ni = 0; ni < 8; ++ni) sacc[ni] = vzero;
#define STAGE_K(bi, kk) do { \
    _Pragma("unroll") \
    for (int r = 0; r < 2; ++r) { \
      int rowb = (w << 4) + (r << 6); \
      gload16(kbase + (long long)(rowb + srow) * DQK_ + (kk) * 32 + sunit, \
              &smem[12800 + (bi) * 4096 + rowb * 32]); \
    } } while (0)
    STAGE_K(0, 0);
    for (int ks = 0; ks < 6; ++ks) {
      if (ks < 5) { STAGE_K((ks + 1) & 1, ks + 1); wait_vm2(); }
      else wait_vm0();
      __builtin_amdgcn_s_barrier();
      const int kb = 12800 + (ks & 1) * 4096;
      short8_t aq = *reinterpret_cast<const short8_t*>(
          &smem[(rb + lr) * 200 + ks * 32 + rsw]);
      __builtin_amdgcn_s_setprio(1);
      #pragma unroll
      for (int ni = 0; ni < 8; ++ni) {
        short8_t bk = *reinterpret_cast<const short8_t*>(&smem[kb + ((ni << 4) + lr) * 32 + rsw]);
        sacc[ni] = __builtin_amdgcn_mfma_f32_16x16x32_bf16(
            __builtin_bit_cast(bf16x8_t, aq),
            __builtin_bit_cast(bf16x8_t, bk),
            sacc[ni], 0, 0, 0);
      }
      __builtin_amdgcn_s_setprio(0);
      __builtin_amdgcn_s_barrier();
    }
#undef STAGE_K
    #pragma unroll
    for (int rr = 0; rr < 4; ++rr) {
      float sv[8];
      float mx = -3e38f;
      #pragma unroll
      for (int ni = 0; ni < 8; ++ni) {
        sv[ni] = b2f(f2b(sacc[ni][rr])) * scale;
        mx = fmaxf(mx, sv[ni]);
      }
      #pragma unroll
      for (int d = 1; d < 16; d <<= 1) mx = fmaxf(mx, __shfl_xor(mx, d, 64));
      float mnew = fmaxf(mrow[rr], mx);
      float corr = expf(mrow[rr] - mnew);
      float psum = 0.f;
      short pb[8];
      #pragma unroll
      for (int ni = 0; ni < 8; ++ni) {
        float p = expf(sv[ni] - mnew);
        pb[ni] = f2b(p);
        psum += p;
      }
      #pragma unroll
      for (int d = 1; d < 16; d <<= 1) psum += __shfl_xor(psum, d, 64);
      lrow[rr] = lrow[rr] * corr + psum;
      mrow[rr] = mnew;
      int row = rb + (g << 2) + rr;
      int xr = (row >> 1) & 3;
      #pragma unroll
      for (int ni = 0; ni < 8; ++ni) {
        int cc = (ni << 4) + lr;
        int scc = (cc & ~31) | (((((cc >> 3) & 3) ^ xr)) << 3) | (cc & 7);
        smem[20992 + row * 136 + scc] = pb[ni];
      }
      #pragma unroll
      for (int ni = 0; ni < 8; ++ni) oacc[ni][rr] *= corr;
    }
    __syncthreads();
    const short* vbase = vh + (kt << 7);
#define STAGE_V(bi, kk) do { \
    _Pragma("unroll") \
    for (int r = 0; r < 2; ++r) { \
      int rowb = (w << 4) + (r << 6); \
      gload16(vbase + (long long)(rowb + srow) * S_LEN + (kk) * 32 + sunit, \
              &smem[29696 + (bi) * 4096 + rowb * 32]); \
    } } while (0)
    STAGE_V(0, 0);
    for (int ks = 0; ks < 4; ++ks) {
      if (ks < 3) { STAGE_V((ks + 1) & 1, ks + 1); wait_vm2(); }
      else wait_vm0();
      __builtin_amdgcn_s_barrier();
      const int vb = 29696 + (ks & 1) * 4096;
      short8_t ap = *reinterpret_cast<const short8_t*>(
          &smem[20992 + (rb + lr) * 136 + ks * 32 + rsw]);
      __builtin_amdgcn_s_setprio(1);
      #pragma unroll
      for (int ni = 0; ni < 8; ++ni) {
        short8_t bv = *reinterpret_cast<const short8_t*>(&smem[vb + ((ni << 4) + lr) * 32 + rsw]);
        oacc[ni] = __builtin_amdgcn_mfma_f32_16x16x32_bf16(
            __builtin_bit_cast(bf16x8_t, ap),
            __builtin_bit_cast(bf16x8_t, bv),
            oacc[ni], 0, 0, 0);
      }
      __builtin_amdgcn_s_setprio(0);
      __builtin_amdgcn_s_barrier();
    }
#undef STAGE_V
  }
  __syncthreads();
  #pragma unroll
  for (int ni = 0; ni < 8; ++ni)
    #pragma unroll
    for (int rr = 0; rr < 4; ++rr) {
      int row = rb + (g << 2) + rr;
      smem[20992 + row * 136 + (ni << 4) + lr] = f2b(oacc[ni][rr] / lrow[rr]);
    }
  __syncthreads();
  {
    int row = tid >> 2, quarter = (tid & 3) << 5;
    #pragma unroll
    for (int j = 0; j < 4; ++j) {
      int col = quarter + (j << 3);
      short8_t v = *reinterpret_cast<const short8_t*>(&smem[20992 + row * 136 + col]);
      *reinterpret_cast<short8_t*>(&ao[(long long)(q0 + row) * HDIM + (h << 7) + col]) = v;
    }
  }
}

// ---------------- small kernels ----------------
__global__ void __launch_bounds__(64)
rope_tables_kernel(float* cosT, float* sinT) {
  int s = blockIdx.x, j = threadIdx.x;
  int i = j & 31;
  float inv = powf(10000.0f, -((float)(2 * i) / 64.0f));
  float ang = (float)s * inv;
  cosT[s * 64 + j] = cosf(ang);
  sinT[s * 64 + j] = sinf(ang);
}

__global__ void __launch_bounds__(256)
rmsnorm_bf16_kernel(const short* __restrict__ in, long long istride,
                    const short* __restrict__ w,
                    short* __restrict__ out, long long ostride, int D) {
  const short* x = in + (long long)blockIdx.x * istride;
  short* o = out + (long long)blockIdx.x * ostride;
  const int nc = D >> 3;
  float ss = 0.f;
  for (int c = threadIdx.x; c < nc; c += 256) {
    short8_t v = reinterpret_cast<const short8_t*>(x)[c];
    #pragma unroll
    for (int j = 0; j < 8; ++j) { float f = b2f(v[j]); ss += f * f; }
  }
  __shared__ float red[256];
  red[threadIdx.x] = ss; __syncthreads();
  for (int s2 = 128; s2 > 0; s2 >>= 1) {
    if (threadIdx.x < s2) red[threadIdx.x] += red[threadIdx.x + s2];
    __syncthreads();
  }
  float r = 1.0f / sqrtf(red[0] / (float)D + 1e-6f);
  for (int c = threadIdx.x; c < nc; c += 256) {
    short8_t v = reinterpret_cast<const short8_t*>(x)[c];
    short8_t wv = reinterpret_cast<const short8_t*>(w)[c];
    short8_t ov;
    #pragma unroll
    for (int j = 0; j < 8; ++j) ov[j] = f2b(b2f(wv[j]) * (b2f(v[j]) * r));
    reinterpret_cast<short8_t*>(o)[c] = ov;
  }
}

__global__ void __launch_bounds__(256)
build_qf_kernel(const short* q, const float* cosT, const float* sinT, short* qf) {
  int s = blockIdx.x;
  for (int idx = threadIdx.x; idx < NH_ * DQK_; idx += 256) {
    int h = idx / DQK_, d = idx - h * DQK_;
    const short* qr = q + (long long)s * QN_ + h * DQK_;
    float val;
    if (d < 128) val = b2f(qr[d]);
    else {
      int j = d - 128;
      float c = cosT[s * 64 + j], sn = sinT[s * 64 + j];
      float x0 = b2f(qr[128 + j]);
      float rot = (j < 32) ? -b2f(qr[128 + j + 32]) : b2f(qr[128 + j - 32]);
      val = x0 * c + rot * sn;
    }
    qf[(long long)h * S_LEN * DQK_ + (long long)s * DQK_ + d] = f2b(val);
  }
}

__global__ void __launch_bounds__(256)
build_kf_kernel(const short* kvup, const short* krope, long long kstride,
                const float* cosT, const float* sinT, short* kf) {
  int s = blockIdx.x;
  for (int idx = threadIdx.x; idx < NH_ * DQK_; idx += 256) {
    int h = idx / DQK_, d = idx - h * DQK_;
    float val;
    if (d < 128) val = b2f(kvup[(long long)s * KVUPN + h * 256 + d]);
    else {
      int j = d - 128;
      float c = cosT[s * 64 + j], sn = sinT[s * 64 + j];
      const short* kr = krope + (long long)s * kstride;
      float x0 = b2f(kr[j]);
      float rot = (j < 32) ? -b2f(kr[j + 32]) : b2f(kr[j - 32]);
      val = x0 * c + rot * sn;
    }
    kf[(long long)h * S_LEN * DQK_ + (long long)s * DQK_ + d] = f2b(val);
  }
}

__global__ void __launch_bounds__(256)
transpose_v_kernel(const short* kvup, short* vT) {
  int h = blockIdx.z;
  int r0 = blockIdx.y * 32, c0 = blockIdx.x * 32;
  int tx = threadIdx.x & 31, ty = threadIdx.x >> 5;
  __shared__ short tile[32][33];
  #pragma unroll
  for (int i = 0; i < 4; ++i)
    tile[ty + i * 8][tx] =
        kvup[(long long)(r0 + ty + i * 8) * KVUPN + h * 256 + 128 + c0 + tx];
  __syncthreads();
  short* d = vT + (long long)h * 128 * S_LEN;
  #pragma unroll
  for (int i = 0; i < 4; ++i)
    d[(long long)(c0 + ty + i * 8) * S_LEN + r0 + tx] = tile[tx][ty + i * 8];
}

__global__ void __launch_bounds__(256)
gate_kernel(const short* x2, const short* gw, int* cnt, int* elist, float* ewt, int* tok2slot) {
  int t = blockIdx.x;
  int e = threadIdx.x >> 5, j = threadIdx.x & 31;
  const short* x = x2 + (long long)t * HDIM;
  float acc = 0.f;
  for (int k = j; k < HDIM; k += 32) acc += b2f(x[k]) * b2f(gw[(long long)k * EXP_ + e]);
  __shared__ float red[8][32];
  red[e][j] = acc; __syncthreads();
  for (int s2 = 16; s2 > 0; s2 >>= 1) {
    if (j < s2) red[e][j] += red[e][j + s2];
    __syncthreads();
  }
  if (threadIdx.x == 0) {
    float l[8], p[8];
    float m = -1e30f;
    for (int q = 0; q < 8; ++q) { l[q] = b2f(f2b(red[q][0])); m = fmaxf(m, l[q]); }
    float sum = 0.f;
    for (int q = 0; q < 8; ++q) { p[q] = expf(l[q] - m); sum += p[q]; }
    int i0 = 0; for (int q = 1; q < 8; ++q) if (p[q] > p[i0]) i0 = q;
    int i1 = (i0 == 0) ? 1 : 0;
    for (int q = 0; q < 8; ++q) if (q != i0 && p[q] > p[i1]) i1 = q;
    float denom = p[i0] + p[i1];
    float w0 = b2f(f2b(p[i0] / denom));
    float w1 = b2f(f2b(p[i1] / denom));
    int pos0 = atomicAdd(&cnt[i0], 1);
    int pos1 = atomicAdd(&cnt[i1], 1);
    elist[i0 * S_LEN + pos0] = t;  ewt[i0 * S_LEN + pos0] = w0;
    elist[i1 * S_LEN + pos1] = t;  ewt[i1 * S_LEN + pos1] = w1;
    int4* slot = (int4*)tok2slot;
    slot[t] = make_int4(i0, pos0, i1, pos1);
  }
}

__global__ void __launch_bounds__(256)
moe_combine_kernel(short* h, const short* shared_out, const short* routed,
                   const int* tok2slot) {
  int t = blockIdx.x;
  const int4 sl = ((const int4*)tok2slot)[t];
  const short8_t* s0 = reinterpret_cast<const short8_t*>(shared_out + (long long)t * HDIM);
  const short8_t* s1 = reinterpret_cast<const short8_t*>(shared_out + ((long long)S_LEN + t) * HDIM);
  const short8_t* r0 = reinterpret_cast<const short8_t*>(
      routed + ((long long)sl.x * S_LEN + sl.y) * HDIM);
  const short8_t* r1 = reinterpret_cast<const short8_t*>(
      routed + ((long long)sl.z * S_LEN + sl.w) * HDIM);
  long long c = (long long)t * 256 + threadIdx.x;
  short8_t hv = reinterpret_cast<short8_t*>(h)[c];
  short8_t a0 = s0[threadIdx.x], a1 = s1[threadIdx.x];
  short8_t v0 = r0[threadIdx.x], v1 = r1[threadIdx.x];
  short8_t ov;
  #pragma unroll
  for (int j = 0; j < 8; ++j)
    ov[j] = f2b(b2f(hv[j]) + (b2f(a0[j]) + b2f(a1[j]) + b2f(v0[j]) + b2f(v1[j])));
  reinterpret_cast<short8_t*>(h)[c] = ov;
}

// ---------------- pooling ----------------
template<int AF32, int OUTBF16>
__global__ void __launch_bounds__(256)
gemv_bt_kernel(const void* a, const short* __restrict__ BT, void* out, int K) {
  int n = blockIdx.x;
  const short8_t* row = reinterpret_cast<const short8_t*>(BT + (long long)n * K);
  float acc = 0.f;
  for (int c = threadIdx.x; c < (K >> 3); c += 256) {
    short8_t v = row[c];
    if (AF32) {
      f32x4 a0 = reinterpret_cast<const f32x4*>(a)[2 * c];
      f32x4 a1 = reinterpret_cast<const f32x4*>(a)[2 * c + 1];
      #pragma unroll
      for (int j = 0; j < 4; ++j) {
        acc += a0[j] * b2f(v[j]);
        acc += a1[j] * b2f(v[4 + j]);
      }
    } else {
      short8_t av = reinterpret_cast<const short8_t*>(a)[c];
      #pragma unroll
      for (int j = 0; j < 8; ++j) acc += b2f(av[j]) * b2f(v[j]);
    }
  }
  __shared__ float red[256];
  red[threadIdx.x] = acc; __syncthreads();
  for (int s2 = 128; s2 > 0; s2 >>= 1) {
    if (threadIdx.x < s2) red[threadIdx.x] += red[threadIdx.x + s2];
    __syncthreads();
  }
  if (threadIdx.x == 0) {
    if (OUTBF16) ((short*)out)[n] = f2b(red[0]);
    else         ((float*)out)[n] = red[0];
  }
}

__global__ void __launch_bounds__(256)
pool_score_kernel(const short* qv, const short* kmat, float* score) {
  int s = blockIdx.x;
  const short8_t* kr = reinterpret_cast<const short8_t*>(kmat + (long long)s * HDIM);
  const short8_t* qr = reinterpret_cast<const short8_t*>(qv);
  short8_t kv8 = kr[threadIdx.x], qv8 = qr[threadIdx.x];
  float acc = 0.f;
  #pragma unroll
  for (int j = 0; j < 8; ++j) acc += b2f(qv8[j]) * b2f(kv8[j]);
  __shared__ float red[256];
  red[threadIdx.x] = acc; __syncthreads();
  for (int s2 = 128; s2 > 0; s2 >>= 1) {
    if (threadIdx.x < s2) red[threadIdx.x] += red[threadIdx.x + s2];
    __syncthreads();
  }
  if (threadIdx.x == 0) score[s] = b2f(f2b(red[0])) * 0.022097086912079608f;
}

__global__ void __launch_bounds__(256)
softmax_vec_kernel(float* v) {
  int tid = threadIdx.x;
  float f[8]; float m = -1e30f;
  #pragma unroll
  for (int i = 0; i < 8; ++i) { f[i] = v[i * 256 + tid]; m = fmaxf(m, f[i]); }
  __shared__ float red[256];
  red[tid] = m; __syncthreads();
  for (int s2 = 128; s2 > 0; s2 >>= 1) {
    if (tid < s2) red[tid] = fmaxf(red[tid], red[tid + s2]);
    __syncthreads();
  }
  m = red[0]; __syncthreads();
  float sum = 0.f;
  #pragma unroll
  for (int i = 0; i < 8; ++i) { f[i] = expf(f[i] - m); sum += f[i]; }
  red[tid] = sum; __syncthreads();
  for (int s2 = 128; s2 > 0; s2 >>= 1) {
    if (tid < s2) red[tid] += red[tid + s2];
    __syncthreads();
  }
  float inv = 1.0f / red[0];
  #pragma unroll
  for (int i = 0; i < 8; ++i) v[i * 256 + tid] = f[i] * inv;
}

__global__ void __launch_bounds__(256)
pool_wsum_t_kernel(const float* w, const short* vT, float* pooled) {
  int h = blockIdx.x;
  const short8_t* row = reinterpret_cast<const short8_t*>(vT + (long long)h * S_LEN);
  int c = threadIdx.x;
  short8_t v = row[c];
  f32x4 w0 = reinterpret_cast<const f32x4*>(w)[2 * c];
  f32x4 w1 = reinterpret_cast<const f32x4*>(w)[2 * c + 1];
  float acc = 0.f;
  #pragma unroll
  for (int j = 0; j < 4; ++j) {
    acc += w0[j] * b2f(v[j]);
    acc += w1[j] * b2f(v[4 + j]);
  }
  __shared__ float red[256];
  red[threadIdx.x] = acc; __syncthreads();
  for (int s2 = 128; s2 > 0; s2 >>= 1) {
    if (threadIdx.x < s2) red[threadIdx.x] += red[threadIdx.x + s2];
    __syncthreads();
  }
  if (threadIdx.x == 0) pooled[h] = red[0];
}

__global__ void __launch_bounds__(256)
rmsnorm_f32_kernel(const float* x, const short* w, float* out) {
  int tid = threadIdx.x;
  float f[8]; float ss = 0.f;
  #pragma unroll
  for (int i = 0; i < 8; ++i) { f[i] = x[i * 256 + tid]; ss += f[i] * f[i]; }
  __shared__ float red[256];
  red[tid] = ss; __syncthreads();
  for (int s2 = 128; s2 > 0; s2 >>= 1) {
    if (tid < s2) red[tid] += red[tid + s2];
    __syncthreads();
  }
  float r = 1.0f / sqrtf(red[0] / 2048.0f + 1e-6f);
  #pragma unroll
  for (int i = 0; i < 8; ++i) out[i * 256 + tid] = b2f(w[i * 256 + tid]) * (f[i] * r);
}

// ---------------- host ----------------
extern "C" void kernel_launch(void* const* d_in, const int* in_sizes, int n_in,
                              void* d_out, int out_size, void* d_ws, size_t ws_size,
                              hipStream_t stream)
{
  (void)n_in; (void)out_size; (void)ws_size;
  const int* ids = (const int*)d_in[24];

  char* base = (char*)d_ws;
  size_t off = 0;
  auto alloc = [&](size_t bytes) -> void* {
    void* p = base + off;
    off += (bytes + 255) & ~(size_t)255;
    return p;
  };

  int* dflag = (int*)alloc(256);

  short* qkvdwT = (short*)alloc((size_t)2 * DCAT * HDIM * 2);
  short* quwT  = (short*)alloc((size_t)2 * QN_ * QRANK_ * 2);
  short* kvuwT = (short*)alloc((size_t)2 * KVUPN * KVRANK_ * 2);
  short* opwT  = (short*)alloc((size_t)2 * HDIM * HDIM * 2);
  short* rw13T = (short*)alloc((size_t)16 * IFF2 * HDIM * 2);
  short* rw2T  = (short*)alloc((size_t)16 * HDIM * IFF_ * 2);
  short* sw13T = (short*)alloc((size_t)4 * IFF2 * HDIM * 2);
  short* sw2T  = (short*)alloc((size_t)4 * HDIM * IFF_ * 2);
  short* pqwT  = (short*)alloc((size_t)HDIM * HDIM * 2);
  short* pkwT  = (short*)alloc((size_t)HDIM * HDIM * 2);
  short* pvwT  = (short*)alloc((size_t)HDIM * HDIM * 2);
  short* powT  = (short*)alloc((size_t)PD_ * HDIM * 2);
  short* ln1w = (short*)alloc((size_t)in_sizes[1] * 2);
  short* qnw  = (short*)alloc((size_t)in_sizes[3] * 2);
  short* kvnw = (short*)alloc((size_t)in_sizes[6] * 2);
  short* ln2w = (short*)alloc((size_t)in_sizes[9] * 2);
  short* gatw = (short*)alloc((size_t)in_sizes[10] * 2);
  short* fnww = (short*)alloc((size_t)in_sizes[17] * 2);
  short* lqw  = (short*)alloc((size_t)in_sizes[18] * 2);
  short* pnww = (short*)alloc((size_t)in_sizes[23] * 2);

  float* cosT    = (float*)alloc((size_t)S_LEN * 64 * 4);
  float* sinT    = (float*)alloc((size_t)S_LEN * 64 * 4);
  short* hbuf    = (short*)alloc((size_t)S_LEN * HDIM * 2);
  short* xbuf    = (short*)alloc((size_t)S_LEN * HDIM * 2);
  short* dcat    = (short*)alloc((size_t)S_LEN * DCAT * 2);
  short* qlatn   = (short*)alloc((size_t)S_LEN * QRANK_ * 2);
  short* qbuf    = (short*)alloc((size_t)S_LEN * QN_ * 2);
  short* kvn     = (short*)alloc((size_t)S_LEN * KVRANK_ * 2);
  short* kvup    = (short*)alloc((size_t)S_LEN * KVUPN * 2);
  short* qf      = (short*)alloc((size_t)NH_ * S_LEN * DQK_ * 2);
  short* kf      = (short*)alloc((size_t)NH_ * S_LEN * DQK_ * 2);
  short* vT      = (short*)alloc((size_t)NH_ * 128 * S_LEN * 2);
  short* ao      = (short*)alloc((size_t)S_LEN * HDIM * 2);
  short* hfin    = (short*)alloc((size_t)S_LEN * HDIM * 2);
  short* kpool   = (short*)alloc((size_t)S_LEN * HDIM * 2);
  short* vpoolT  = (short*)alloc((size_t)HDIM * S_LEN * 2);
  short* qvec    = (short*)alloc((size_t)HDIM * 2);
  float* pscore  = (float*)alloc((size_t)S_LEN * 4);
  float* pooled  = (float*)alloc((size_t)HDIM * 4);
  float* pooledn = (float*)alloc((size_t)HDIM * 4);
  int*   ecnt    = (int*)alloc(64);
  int*   elist   = (int*)alloc((size_t)EXP_ * S_LEN * 4);
  float* ewt     = (float*)alloc((size_t)EXP_ * S_LEN * 4);
  int*   tok2slot= (int*)alloc((size_t)S_LEN * 16);
  short* gba_e   = (short*)alloc((size_t)EXP_ * S_LEN * IFF_ * 2);
  short* routed  = (short*)alloc((size_t)EXP_ * S_LEN * HDIM * 2);
  short* gsh1    = (short*)alloc((size_t)S_LEN * IFF2 * 2);
  short* shared_out = (short*)alloc((size_t)2 * S_LEN * HDIM * 2);

  detect_kernel<<<1, 256, 0, stream>>>(d_in[0], dflag);

  auto tconv = [&](const void* src, short* dst, int R, int C, int nslabs,
                   long long sSrc, long long sDst, int rowMul, int rowOff) {
    dim3 grid(C / 32, R / 32, nslabs);
    transconv_kernel<<<grid, 256, 0, stream>>>(src, dst, R, C, dflag, sSrc, sDst, rowMul, rowOff);
  };
  auto pconv = [&](const void* src, short* dst, long long n) {
    long long nchunks = n / 8;
    int blocks = (int)((nchunks + 255) / 256);
    if (blocks > 2048) blocks = 2048;
    if (blocks < 1) blocks = 1;
    convert_kernel<<<blocks, 256, 0, stream>>>(src, dst, nchunks, dflag);
  };

  tconv(d_in[2], qkvdwT, HDIM, QRANK_, 2,
        (long long)HDIM * QRANK_, (long long)DCAT * HDIM, 1, 0);
  tconv(d_in[5], qkvdwT + (size_t)QRANK_ * HDIM, HDIM, KVDN, 2,
        (long long)HDIM * KVDN, (long long)DCAT * HDIM, 1, 0);
  tconv(d_in[4],  quwT,  QRANK_, QN_,  2, (long long)QRANK_ * QN_,  (long long)QN_ * QRANK_, 1, 0);
  tconv(d_in[7],  kvuwT, KVRANK_,KVUPN,2, (long long)KVRANK_ * KVUPN,(long long)KVUPN * KVRANK_, 1, 0);
  tconv(d_in[8],  opwT,  HDIM,   HDIM, 2, (long long)HDIM * HDIM,   (long long)HDIM * HDIM, 1, 0);
  tconv(d_in[11], rw13T, HDIM,   IFF_, 16,(long long)HDIM * IFF_,   (long long)IFF2 * HDIM, 2, 0);
  tconv(d_in[13], rw13T, HDIM,   IFF_, 16,(long long)HDIM * IFF_,   (long long)IFF2 * HDIM, 2, 1);
  tconv(d_in[12], rw2T,  IFF_,   HDIM, 16,(long long)IFF_ * HDIM,   (long long)HDIM * IFF_, 1, 0);
  tconv(d_in[14], sw13T, HDIM,   IFF_, 4, (long long)HDIM * IFF_,   (long long)IFF2 * HDIM, 2, 0);
  tconv(d_in[16], sw13T, HDIM,   IFF_, 4, (long long)HDIM * IFF_,   (long long)IFF2 * HDIM, 2, 1);
  tconv(d_in[15], sw2T,  IFF_,   HDIM, 4, (long long)IFF_ * HDIM,   (long long)HDIM * IFF_, 1, 0);
  tconv(d_in[19], pqwT,  HDIM,   HDIM, 1, 0, 0, 1, 0);
  tconv(d_in[20], pkwT,  HDIM,   HDIM, 1, 0, 0, 1, 0);
  tconv(d_in[21], pvwT,  HDIM,   HDIM, 1, 0, 0, 1, 0);
  tconv(d_in[22], powT,  HDIM,   PD_,  1, 0, 0, 1, 0);
  pconv(d_in[1],  ln1w, in_sizes[1]);
  pconv(d_in[3],  qnw,  in_sizes[3]);
  pconv(d_in[6],  kvnw, in_sizes[6]);
  pconv(d_in[9],  ln2w, in_sizes[9]);
  pconv(d_in[10], gatw, in_sizes[10]);
  pconv(d_in[17], fnww, in_sizes[17]);
  pconv(d_in[18], lqw,  in_sizes[18]);
  pconv(d_in[23], pnww, in_sizes[23]);

  const float qk_scale = 1.0f / sqrtf((float)DQK_);

  auto gemm = [&](int epi, const short* A, const short* B, short* C,
                  int M, int N, int K, int lda, int ldb, int ldc,
                  int batch, long long sA, long long sB, long long sC) {
    dim3 grid((N + 127) / 128, M / 128, batch);
    if (epi == 0)
      gemm_kernel<0><<<grid, 256, 0, stream>>>(A, B, C, M, N, K, lda, ldb, ldc, sA, sB, sC);
    else if (epi == 1)
      gemm_kernel<1><<<grid, 256, 0, stream>>>(A, B, C, M, N, K, lda, ldb, ldc, sA, sB, sC);
    else
      gemm_kernel<2><<<grid, 256, 0, stream>>>(A, B, C, M, N, K, lda, ldb, ldc, sA, sB, sC);
  };

  rope_tables_kernel<<<S_LEN, 64, 0, stream>>>(cosT, sinT);
  embed_convert_kernel<<<S_LEN, 256, 0, stream>>>(ids, d_in[0], dflag, hbuf);

  for (int l = 0; l < 2; ++l) {
    const short* w_ln1  = ln1w + (size_t)l * HDIM;
    const short* w_qkvT = qkvdwT + (size_t)l * DCAT * HDIM;
    const short* w_qn   = qnw  + (size_t)l * QRANK_;
    const short* w_quT  = quwT + (size_t)l * QN_ * QRANK_;
    const short* w_kvn  = kvnw + (size_t)l * KVRANK_;
    const short* w_kvuT = kvuwT+ (size_t)l * KVUPN * KVRANK_;
    const short* w_opT  = opwT + (size_t)l * HDIM * HDIM;
    const short* w_ln2  = ln2w + (size_t)l * HDIM;
    const short* w_gat  = gatw + (size_t)l * HDIM * EXP_;

    // --- attention ---
    rmsnorm_bf16_kernel<<<S_LEN, 256, 0, stream>>>(hbuf, HDIM, w_ln1, xbuf, HDIM, HDIM);
    gemm(0, xbuf, w_qkvT, dcat, S_LEN, DCAT, HDIM, HDIM, HDIM, DCAT, 1, 0, 0, 0);
    rmsnorm_bf16_kernel<<<S_LEN, 256, 0, stream>>>(dcat, DCAT, w_qn, qlatn, QRANK_, QRANK_);
    gemm(0, qlatn, w_quT, qbuf, S_LEN, QN_, QRANK_, QRANK_, QRANK_, QN_, 1, 0, 0, 0);
    rmsnorm_bf16_kernel<<<S_LEN, 256, 0, stream>>>(dcat + QRANK_, DCAT, w_kvn, kvn, KVRANK_, KVRANK_);
    gemm(0, kvn, w_kvuT, kvup, S_LEN, KVUPN, KVRANK_, KVRANK_, KVRANK_, KVUPN, 1, 0, 0, 0);
    build_qf_kernel<<<S_LEN, 256, 0, stream>>>(qbuf, cosT, sinT, qf);
    build_kf_kernel<<<S_LEN, 256, 0, stream>>>(kvup, dcat + QRANK_ + KVRANK_, DCAT, cosT, sinT, kf);
    {
      dim3 tg(128 / 32, S_LEN / 32, NH_);
      transpose_v_kernel<<<tg, 256, 0, stream>>>(kvup, vT);
    }
    {
      dim3 fg(S_LEN / 64, NH_);
      flash_kernel<<<fg, 256, 0, stream>>>(qf, kf, vT, ao, qk_scale);
    }
    gemm(2, ao, w_opT, hbuf, S_LEN, HDIM, HDIM, HDIM, HDIM, HDIM, 1, 0, 0, 0);

    // --- MoE ---
    rmsnorm_bf16_kernel<<<S_LEN, 256, 0, stream>>>(hbuf, HDIM, w_ln2, xbuf, HDIM, HDIM);
    hipMemsetAsync(ecnt, 0, 64, stream);
    gate_kernel<<<S_LEN, 256, 0, stream>>>(xbuf, w_gat, ecnt, elist, ewt, tok2slot);
    {
      const short* a13 = sw13T + (size_t)l * 2 * IFF2 * HDIM;
      const short* a2  = sw2T  + (size_t)l * 2 * HDIM * IFF_;
      gemm(1, xbuf, a13, gsh1, S_LEN, 2 * IFF2, HDIM, HDIM, HDIM, IFF2, 1, 0, 0, 0);
      gemm(0, gsh1, a2, shared_out, S_LEN, HDIM, IFF_, IFF2, IFF_, HDIM, 2,
           (long long)IFF_, (long long)HDIM * IFF_, (long long)S_LEN * HDIM);
    }
    {
      const short* b13 = rw13T + (size_t)l * 8 * IFF2 * HDIM;
      const short* b2  = rw2T  + (size_t)l * 8 * HDIM * IFF_;
      dim3 g13(IFF2 / 128, S_LEN / 128, EXP_);
      moe_gemm_kernel<1, 1><<<g13, 256, 0, stream>>>(
          xbuf, elist, ecnt, b13, gba_e, ewt, IFF2, HDIM, HDIM, HDIM, IFF_,
          0, (long long)IFF2 * HDIM, (long long)S_LEN * IFF_);
      dim3 g2(HDIM / 128, S_LEN / 128, EXP_);
      moe_gemm_kernel<0, 0><<<g2, 256, 0, stream>>>(
          gba_e, elist, ecnt, b2, routed, nullptr, HDIM, IFF_, IFF_, IFF_, HDIM,
          (long long)S_LEN * IFF_, (long long)HDIM * IFF_, (long long)S_LEN * HDIM);
      moe_combine_kernel<<<S_LEN, 256, 0, stream>>>(hbuf, shared_out, routed, tok2slot);
    }
  }

  // --- attention pooling head ---
  rmsnorm_bf16_kernel<<<S_LEN, 256, 0, stream>>>(hbuf, HDIM, fnww, hfin, HDIM, HDIM);
  gemm(0, hfin, pkwT, kpool, S_LEN, HDIM, HDIM, HDIM, HDIM, HDIM, 1, 0, 0, 0);
  gemm(0, pvwT, hfin, vpoolT, HDIM, S_LEN, HDIM, HDIM, HDIM, S_LEN, 1, 0, 0, 0);
  gemv_bt_kernel<0,1><<<HDIM, 256, 0, stream>>>(lqw, pqwT, qvec, HDIM);
  pool_score_kernel<<<S_LEN, 256, 0, stream>>>(qvec, kpool, pscore);
  softmax_vec_kernel<<<1, 256, 0, stream>>>(pscore);
  pool_wsum_t_kernel<<<HDIM, 256, 0, stream>>>(pscore, vpoolT, pooled);
  rmsnorm_f32_kernel<<<1, 256, 0, stream>>>(pooled, pnww, pooledn);
  gemv_bt_kernel<1,0><<<PD_, 256, 0, stream>>>(pooledn, powT, (float*)d_out, HDIM);
}